// Round 1
// baseline (267.698 us; speedup 1.0000x reference)
//
#include <hip/hip_runtime.h>
#include <hip/hip_bf16.h>

#define B_   2
#define T_   2048
#define D_   1024
#define NH_  16
#define NKV_ 4
#define HD_  64
#define E_   1536  // (NH + 2*NKV) * HD

typedef __attribute__((ext_vector_type(8))) __bf16 bf16x8;
typedef __attribute__((ext_vector_type(4))) float f32x4;

static __device__ __forceinline__ unsigned short f2bf(float f) {
  union { float f; unsigned int u; } c; c.f = f;
  unsigned int r = (c.u + 0x7fffu + ((c.u >> 16) & 1u)) >> 16;
  return (unsigned short)r;
}

// ---------------- fp32 -> bf16 convert (8 elems/thread) ----------------
__global__ void k_f32_to_bf16(const float* __restrict__ in,
                              unsigned short* __restrict__ out, int n8) {
  int i = blockIdx.x * blockDim.x + threadIdx.x;
  if (i >= n8) return;
  const float4* p = (const float4*)in + (size_t)i * 2;
  float4 a = p[0], b = p[1];
  uint4 o;
  o.x = (unsigned)f2bf(a.x) | ((unsigned)f2bf(a.y) << 16);
  o.y = (unsigned)f2bf(a.z) | ((unsigned)f2bf(a.w) << 16);
  o.z = (unsigned)f2bf(b.x) | ((unsigned)f2bf(b.y) << 16);
  o.w = (unsigned)f2bf(b.z) | ((unsigned)f2bf(b.w) << 16);
  ((uint4*)out)[i] = o;
}

// ---------------- float4 copy ----------------
__global__ void k_copy_f32(const float4* __restrict__ in, float4* __restrict__ out, int n4) {
  int i = blockIdx.x * blockDim.x + threadIdx.x;
  if (i < n4) out[i] = in[i];
}

// ---------------- GEMM: C[M,N] = A[M,K] * W[N,K]^T  (bf16 in, fp32 out) ----------------
// 128x128 tile, BK=32, 256 threads = 4 waves (2x2), each wave 64x64 = 4x4 MFMA frags.
__global__ __launch_bounds__(256) void k_gemm_bt(
    const unsigned short* __restrict__ A,
    const unsigned short* __restrict__ W,
    float* __restrict__ C, int M, int N, int K) {
  __shared__ __align__(16) unsigned short As[128][40];
  __shared__ __align__(16) unsigned short Ws[128][40];
  int tid = threadIdx.x;
  int w = tid >> 6, l = tid & 63, lo = l & 15, hi = l >> 4;
  int wm = w >> 1, wn = w & 1;
  int bm = blockIdx.y, bn = blockIdx.x;

  f32x4 acc[4][4];
#pragma unroll
  for (int i = 0; i < 4; ++i)
#pragma unroll
    for (int j = 0; j < 4; ++j) acc[i][j] = (f32x4){0.f, 0.f, 0.f, 0.f};

  const unsigned short* Ab = A + (size_t)bm * 128 * K;
  const unsigned short* Wb = W + (size_t)bn * 128 * K;

  for (int k0 = 0; k0 < K; k0 += 32) {
#pragma unroll
    for (int i = 0; i < 2; ++i) {
      int cid = tid + i * 256;
      int r = cid >> 2, c = (cid & 3) * 8;
      *(bf16x8*)(&As[r][c]) = *(const bf16x8*)(Ab + (size_t)r * K + k0 + c);
      *(bf16x8*)(&Ws[r][c]) = *(const bf16x8*)(Wb + (size_t)r * K + k0 + c);
    }
    __syncthreads();
    bf16x8 af[4], bfr[4];
#pragma unroll
    for (int mi = 0; mi < 4; ++mi) af[mi] = *(const bf16x8*)(&As[wm * 64 + mi * 16 + lo][hi * 8]);
#pragma unroll
    for (int ni = 0; ni < 4; ++ni) bfr[ni] = *(const bf16x8*)(&Ws[wn * 64 + ni * 16 + lo][hi * 8]);
#pragma unroll
    for (int mi = 0; mi < 4; ++mi)
#pragma unroll
      for (int ni = 0; ni < 4; ++ni)
        acc[mi][ni] = __builtin_amdgcn_mfma_f32_16x16x32_bf16(af[mi], bfr[ni], acc[mi][ni], 0, 0, 0);
    __syncthreads();
  }

#pragma unroll
  for (int mi = 0; mi < 4; ++mi) {
#pragma unroll
    for (int r = 0; r < 4; ++r) {
      int row = bm * 128 + wm * 64 + mi * 16 + hi * 4 + r;
      float* cp = C + (size_t)row * N + bn * 128 + wn * 64 + lo;
#pragma unroll
      for (int ni = 0; ni < 4; ++ni) cp[ni * 16] = acc[mi][ni][r];
    }
  }
}

// ---------------- transform: rope(q,k)+scale fold, v-mix, fp32->bf16 ----------------
// one thread per (b, t, job); jobs: 0..15 q heads, 16..19 k heads, 20..35 v_eff heads
__global__ void k_transform(const float* __restrict__ qkv,
                            const float* __restrict__ cosT, const float* __restrict__ sinT,
                            const float* __restrict__ v0,
                            const float* __restrict__ vrl_alpha,
                            const float* __restrict__ qk_scale,
                            unsigned short* __restrict__ qO,
                            unsigned short* __restrict__ kO,
                            unsigned short* __restrict__ vO) {
  int idx = blockIdx.x * blockDim.x + threadIdx.x;
  if (idx >= B_ * T_ * 36) return;
  int bt = idx / 36, job = idx - bt * 36;
  int b = bt / T_, t = bt - b * T_;
  const float* row = qkv + (size_t)bt * E_;
  float v[64];

  if (job < 20) {
    int isq = (job < 16);
    int h = isq ? job : (job - 16);
    const float* src = isq ? (row + h * 64) : (row + NH_ * 64 + h * 64);
#pragma unroll
    for (int i = 0; i < 64; i += 4) {
      float4 f = *(const float4*)(src + i);
      v[i] = f.x; v[i + 1] = f.y; v[i + 2] = f.z; v[i + 3] = f.w;
    }
    const float* cs = cosT + t * 16;
    const float* sn = sinT + t * 16;
#pragma unroll
    for (int d = 0; d < 16; ++d) {
      float c = cs[d], s = sn[d];
      float a = v[d], bb = v[d + 16];
      v[d] = a * c - bb * s;
      v[d + 16] = a * s + bb * c;
    }
    float sc = isq ? (qk_scale[h] * (1.0f / 64.0f)) : 1.0f;
    unsigned short* dst = isq ? (qO + ((size_t)(b * NH_ + h) * T_ + t) * 64)
                              : (kO + ((size_t)(b * NKV_ + h) * T_ + t) * 64);
#pragma unroll
    for (int i = 0; i < 64; i += 8) {
      uint4 o;
      o.x = (unsigned)f2bf(v[i + 0] * sc) | ((unsigned)f2bf(v[i + 1] * sc) << 16);
      o.y = (unsigned)f2bf(v[i + 2] * sc) | ((unsigned)f2bf(v[i + 3] * sc) << 16);
      o.z = (unsigned)f2bf(v[i + 4] * sc) | ((unsigned)f2bf(v[i + 5] * sc) << 16);
      o.w = (unsigned)f2bf(v[i + 6] * sc) | ((unsigned)f2bf(v[i + 7] * sc) << 16);
      *(uint4*)(dst + i) = o;
    }
  } else {
    int h = job - 20;
    const float* src = row + (NH_ + NKV_) * 64 + (h >> 2) * 64;
    const float* v0p = v0 + ((size_t)(b * NH_ + h) * T_ + t) * 64;
    float a = 1.0f / (1.0f + __expf(-vrl_alpha[h]));
    float na = 1.0f - a;
    unsigned short* dst = vO + ((size_t)(b * NH_ + h) * T_ + t) * 64;
#pragma unroll
    for (int i = 0; i < 64; i += 4) {
      float4 f = *(const float4*)(src + i);
      float4 g = *(const float4*)(v0p + i);
      uint2 o;
      o.x = (unsigned)f2bf(na * f.x + a * g.x) | ((unsigned)f2bf(na * f.y + a * g.y) << 16);
      o.y = (unsigned)f2bf(na * f.z + a * g.z) | ((unsigned)f2bf(na * f.w + a * g.w) << 16);
      *(uint2*)(dst + i) = o;
    }
  }
}

// ---------------- flash attention ----------------
// grid (T/64, NH, B), 256 threads = 4 waves; wave w handles q rows [q0+16w, q0+16w+16)
__global__ __launch_bounds__(256) void k_attn(const unsigned short* __restrict__ Q,
                                              const unsigned short* __restrict__ Kp,
                                              const unsigned short* __restrict__ Vp,
                                              unsigned short* __restrict__ Y) {
  int qt = blockIdx.x, h = blockIdx.y, b = blockIdx.z;
  int tid = threadIdx.x;
  int w = tid >> 6, l = tid & 63, lo = l & 15, hi = l >> 4;
  int q0 = qt * 64;
  int kh = h >> 2;

  __shared__ __align__(16) unsigned short Ks[64][72];
  __shared__ __align__(16) unsigned short Vt[64][72];
  __shared__ __align__(16) unsigned short Ps[4][16][72];

  const unsigned short* Qb = Q + ((size_t)(b * NH_ + h) * T_ + q0 + w * 16) * 64;
  bf16x8 qa0 = *(const bf16x8*)(Qb + (size_t)lo * 64 + hi * 8);
  bf16x8 qa1 = *(const bf16x8*)(Qb + (size_t)lo * 64 + 32 + hi * 8);

  f32x4 yacc[4];
#pragma unroll
  for (int nf = 0; nf < 4; ++nf) yacc[nf] = (f32x4){0.f, 0.f, 0.f, 0.f};
  float mrow[4] = {-INFINITY, -INFINITY, -INFINITY, -INFINITY};
  float lrow[4] = {0.f, 0.f, 0.f, 0.f};

  const unsigned short* Kb = Kp + (size_t)(b * NKV_ + kh) * T_ * 64;
  const unsigned short* Vb = Vp + (size_t)(b * NH_ + h) * T_ * 64;

  int ntiles = qt + 1;
  for (int kt = 0; kt < ntiles; ++kt) {
    int kv0 = kt * 64;
    // stage K tile [64 keys][64 feats]
#pragma unroll
    for (int i = 0; i < 2; ++i) {
      int cid = tid + i * 256;
      int r = cid >> 3, c = (cid & 7) * 8;
      *(bf16x8*)(&Ks[r][c]) = *(const bf16x8*)(Kb + (size_t)(kv0 + r) * 64 + c);
    }
    // stage V tile transposed: Vt[feat][key]
#pragma unroll
    for (int i = 0; i < 2; ++i) {
      int cid = tid + i * 256;
      int r = cid >> 3, c = (cid & 7) * 8;
      uint4 vv = *(const uint4*)(Vb + (size_t)(kv0 + r) * 64 + c);
      Vt[c + 0][r] = (unsigned short)(vv.x & 0xffff);
      Vt[c + 1][r] = (unsigned short)(vv.x >> 16);
      Vt[c + 2][r] = (unsigned short)(vv.y & 0xffff);
      Vt[c + 3][r] = (unsigned short)(vv.y >> 16);
      Vt[c + 4][r] = (unsigned short)(vv.z & 0xffff);
      Vt[c + 5][r] = (unsigned short)(vv.z >> 16);
      Vt[c + 6][r] = (unsigned short)(vv.w & 0xffff);
      Vt[c + 7][r] = (unsigned short)(vv.w >> 16);
    }
    __syncthreads();

    // S = Q * K^T  (16 rows x 64 keys per wave)
    f32x4 s[4];
#pragma unroll
    for (int nt = 0; nt < 4; ++nt) {
      f32x4 a = (f32x4){0.f, 0.f, 0.f, 0.f};
      bf16x8 kf0 = *(const bf16x8*)(&Ks[nt * 16 + lo][hi * 8]);
      a = __builtin_amdgcn_mfma_f32_16x16x32_bf16(qa0, kf0, a, 0, 0, 0);
      bf16x8 kf1 = *(const bf16x8*)(&Ks[nt * 16 + lo][32 + hi * 8]);
      a = __builtin_amdgcn_mfma_f32_16x16x32_bf16(qa1, kf1, a, 0, 0, 0);
      s[nt] = a;
    }

    if (kt == qt) {  // diagonal tile: causal mask
#pragma unroll
      for (int nt = 0; nt < 4; ++nt) {
        int col = kv0 + nt * 16 + lo;
#pragma unroll
        for (int r = 0; r < 4; ++r) {
          int rowg = q0 + w * 16 + hi * 4 + r;
          if (col > rowg) s[nt][r] = -INFINITY;
        }
      }
    }

    // online softmax per row
#pragma unroll
    for (int r = 0; r < 4; ++r) {
      float mx = fmaxf(fmaxf(s[0][r], s[1][r]), fmaxf(s[2][r], s[3][r]));
      mx = fmaxf(mx, __shfl_xor(mx, 1));
      mx = fmaxf(mx, __shfl_xor(mx, 2));
      mx = fmaxf(mx, __shfl_xor(mx, 4));
      mx = fmaxf(mx, __shfl_xor(mx, 8));
      float mnew = fmaxf(mrow[r], mx);
      float sc = __expf(mrow[r] - mnew);  // exp(-inf)=0 on first tile
      mrow[r] = mnew;
      lrow[r] *= sc;
#pragma unroll
      for (int nf = 0; nf < 4; ++nf) yacc[nf][r] *= sc;
      float rs = 0.f;
#pragma unroll
      for (int nt = 0; nt < 4; ++nt) {
        float p = __expf(s[nt][r] - mnew);
        s[nt][r] = p;
        rs += p;
      }
      rs += __shfl_xor(rs, 1);
      rs += __shfl_xor(rs, 2);
      rs += __shfl_xor(rs, 4);
      rs += __shfl_xor(rs, 8);
      lrow[r] += rs;
    }

    // write P (bf16) to LDS in [qrow][key] layout for A-fragment reads
#pragma unroll
    for (int nt = 0; nt < 4; ++nt)
#pragma unroll
      for (int r = 0; r < 4; ++r)
        Ps[w][hi * 4 + r][nt * 16 + lo] = f2bf(s[nt][r]);
    __syncthreads();

    // PV: y += P(16x64) * V(64x64)
#pragma unroll
    for (int kc = 0; kc < 2; ++kc) {
      bf16x8 pa = *(const bf16x8*)(&Ps[w][lo][kc * 32 + hi * 8]);
#pragma unroll
      for (int nf = 0; nf < 4; ++nf) {
        bf16x8 vf = *(const bf16x8*)(&Vt[nf * 16 + lo][kc * 32 + hi * 8]);
        yacc[nf] = __builtin_amdgcn_mfma_f32_16x16x32_bf16(pa, vf, yacc[nf], 0, 0, 0);
      }
    }
    __syncthreads();
  }

  // epilogue: divide by row sum, write y[b][t][h*64+f] bf16
#pragma unroll
  for (int r = 0; r < 4; ++r) {
    int t = q0 + w * 16 + hi * 4 + r;
    float inv = 1.0f / lrow[r];
    unsigned short* yp = Y + ((size_t)(b * T_ + t)) * D_ + h * 64;
#pragma unroll
    for (int nf = 0; nf < 4; ++nf) yp[nf * 16 + lo] = f2bf(yacc[nf][r] * inv);
  }
}

extern "C" void kernel_launch(void* const* d_in, const int* in_sizes, int n_in,
                              void* d_out, int out_size, void* d_ws, size_t ws_size,
                              hipStream_t stream) {
  const float* x     = (const float*)d_in[0];
  const float* cosT  = (const float*)d_in[1];
  const float* sinT  = (const float*)d_in[2];
  const float* v0    = (const float*)d_in[3];
  const float* Wqkv  = (const float*)d_in[4];
  const float* Wproj = (const float*)d_in[5];
  const float* vrl   = (const float*)d_in[6];
  const float* qks   = (const float*)d_in[7];
  float* out = (float*)d_out;

  char* ws = (char*)d_ws;
  float*          qkv    = (float*)ws;                            // 25165824 B
  unsigned short* xb     = (unsigned short*)(ws + 25165824);      //  8388608 B
  unsigned short* wqkvb  = (unsigned short*)(ws + 33554432);      //  3145728 B
  unsigned short* wprojb = (unsigned short*)(ws + 36700160);      //  2097152 B
  unsigned short* qb     = (unsigned short*)(ws + 38797312);      //  8388608 B
  unsigned short* kb     = (unsigned short*)(ws + 47185920);      //  2097152 B
  unsigned short* vb     = (unsigned short*)(ws + 49283072);      //  8388608 B
  unsigned short* yb     = (unsigned short*)ws;                   // aliases qkv (dead by then)

  k_f32_to_bf16<<<4194304 / 8 / 256, 256, 0, stream>>>(x, xb, 4194304 / 8);
  k_f32_to_bf16<<<1572864 / 8 / 256, 256, 0, stream>>>(Wqkv, wqkvb, 1572864 / 8);
  k_f32_to_bf16<<<1048576 / 8 / 256, 256, 0, stream>>>(Wproj, wprojb, 1048576 / 8);

  k_gemm_bt<<<dim3(E_ / 128, (B_ * T_) / 128), 256, 0, stream>>>(xb, wqkvb, qkv, B_ * T_, E_, D_);

  k_transform<<<(B_ * T_ * 36) / 256, 256, 0, stream>>>(qkv, cosT, sinT, v0, vrl, qks, qb, kb, vb);

  k_attn<<<dim3(T_ / 64, NH_, B_), 256, 0, stream>>>(qb, kb, vb, yb);

  k_gemm_bt<<<dim3(D_ / 128, (B_ * T_) / 128), 256, 0, stream>>>(yb, wprojb, out, B_ * T_, D_, D_);

  k_copy_f32<<<4194304 / 4 / 256, 256, 0, stream>>>((const float4*)v0, (float4*)(out + 4194304), 4194304 / 4);
}

// Round 2
// 176.716 us; speedup vs baseline: 1.5149x; 1.5149x over previous
//
#include <hip/hip_runtime.h>
#include <hip/hip_bf16.h>

#define B_   2
#define T_   2048
#define D_   1024
#define NH_  16
#define NKV_ 4
#define HD_  64
#define E_   1536  // (NH + 2*NKV) * HD

typedef __attribute__((ext_vector_type(8))) __bf16 bf16x8;
typedef __attribute__((ext_vector_type(4))) float f32x4;

static __device__ __forceinline__ unsigned short f2bf(float f) {
  union { float f; unsigned int u; } c; c.f = f;
  unsigned int r = (c.u + 0x7fffu + ((c.u >> 16) & 1u)) >> 16;
  return (unsigned short)r;
}

// async global->LDS, 16B per lane. LDS dest = wave-uniform base + lane*16.
static __device__ __forceinline__ void gld_lds16(const unsigned short* g, unsigned short* l) {
  __builtin_amdgcn_global_load_lds(
      (const __attribute__((address_space(1))) unsigned int*)(unsigned long long)(const void*)g,
      (__attribute__((address_space(3))) unsigned int*)(unsigned int)(unsigned long long)(void*)l,
      16, 0, 0);
}

// ---------------- fused fp32 -> bf16 converts (8 elems/thread) ----------------
__global__ void k_convert_all(const float* __restrict__ x, const float* __restrict__ wq,
                              const float* __restrict__ wp, unsigned short* __restrict__ xb,
                              unsigned short* __restrict__ wqb, unsigned short* __restrict__ wpb) {
  int i = blockIdx.x * blockDim.x + threadIdx.x;
  const float* src; unsigned short* dst; int j;
  if (i < 524288)      { src = x;  dst = xb;  j = i; }
  else if (i < 720896) { src = wq; dst = wqb; j = i - 524288; }
  else                 { src = wp; dst = wpb; j = i - 720896; }
  const float4* p = (const float4*)src + (size_t)j * 2;
  float4 a = p[0], b = p[1];
  uint4 o;
  o.x = (unsigned)f2bf(a.x) | ((unsigned)f2bf(a.y) << 16);
  o.y = (unsigned)f2bf(a.z) | ((unsigned)f2bf(a.w) << 16);
  o.z = (unsigned)f2bf(b.x) | ((unsigned)f2bf(b.y) << 16);
  o.w = (unsigned)f2bf(b.z) | ((unsigned)f2bf(b.w) << 16);
  ((uint4*)dst)[j] = o;
}

// ---------------- float4 copy ----------------
__global__ void k_copy_f32(const float4* __restrict__ in, float4* __restrict__ out, int n4) {
  int i = blockIdx.x * blockDim.x + threadIdx.x;
  if (i < n4) out[i] = in[i];
}

// ---------------- GEMM (m97 structure): C[M,N] = A[M,K]*W[N,K]^T, bf16 in fp32 out ----------
// 128x128 tile, BK=32, 4 waves, global_load_lds width-16 staging into linear LDS.
__global__ __launch_bounds__(256) void k_gemm_bt(
    const unsigned short* __restrict__ A,
    const unsigned short* __restrict__ W,
    float* __restrict__ C, int M, int N, int K) {
  __shared__ __align__(16) unsigned short As[128 * 32];
  __shared__ __align__(16) unsigned short Ws[128 * 32];
  int tid = threadIdx.x;
  int w = tid >> 6, l = tid & 63, lo = l & 15, hi = l >> 4;
  int wm = w >> 1, wn = w & 1;
  int bm = blockIdx.y, bn = blockIdx.x;

  f32x4 acc[4][4];
#pragma unroll
  for (int i = 0; i < 4; ++i)
#pragma unroll
    for (int j = 0; j < 4; ++j) acc[i][j] = (f32x4){0.f, 0.f, 0.f, 0.f};

  const unsigned short* Ab = A + (size_t)bm * 128 * K;
  const unsigned short* Wb = W + (size_t)bn * 128 * K;
  int sr = l >> 2, sc = (l & 3) * 8;  // staging: lane covers (row sr, 8 cols at sc)

  for (int k0 = 0; k0 < K; k0 += 32) {
#pragma unroll
    for (int i = 0; i < 2; ++i) {
      int rb = w * 32 + i * 16;
      gld_lds16(Ab + (size_t)(rb + sr) * K + k0 + sc, &As[rb * 32]);
      gld_lds16(Wb + (size_t)(rb + sr) * K + k0 + sc, &Ws[rb * 32]);
    }
    __syncthreads();  // drains vmcnt -> LDS tiles ready
    bf16x8 af[4], wf[4];
#pragma unroll
    for (int mi = 0; mi < 4; ++mi) af[mi] = *(const bf16x8*)&As[(wm * 64 + mi * 16 + lo) * 32 + hi * 8];
#pragma unroll
    for (int ni = 0; ni < 4; ++ni) wf[ni] = *(const bf16x8*)&Ws[(wn * 64 + ni * 16 + lo) * 32 + hi * 8];
#pragma unroll
    for (int mi = 0; mi < 4; ++mi)
#pragma unroll
      for (int ni = 0; ni < 4; ++ni)
        acc[mi][ni] = __builtin_amdgcn_mfma_f32_16x16x32_bf16(af[mi], wf[ni], acc[mi][ni], 0, 0, 0);
    __syncthreads();
  }

#pragma unroll
  for (int mi = 0; mi < 4; ++mi) {
#pragma unroll
    for (int r = 0; r < 4; ++r) {
      int row = bm * 128 + wm * 64 + mi * 16 + hi * 4 + r;
      float* cp = C + (size_t)row * N + bn * 128 + wn * 64 + lo;
#pragma unroll
      for (int ni = 0; ni < 4; ++ni) cp[ni * 16] = acc[mi][ni][r];
    }
  }
}

// ---------------- transform: rope(q,k)+scale fold, v-mix, fp32->bf16 ----------------
__global__ void k_transform(const float* __restrict__ qkv,
                            const float* __restrict__ cosT, const float* __restrict__ sinT,
                            const float* __restrict__ v0,
                            const float* __restrict__ vrl_alpha,
                            const float* __restrict__ qk_scale,
                            unsigned short* __restrict__ qO,
                            unsigned short* __restrict__ kO,
                            unsigned short* __restrict__ vO) {
  int idx = blockIdx.x * blockDim.x + threadIdx.x;
  if (idx >= B_ * T_ * 36) return;
  int bt = idx / 36, job = idx - bt * 36;
  int b = bt / T_, t = bt - b * T_;
  const float* row = qkv + (size_t)bt * E_;
  float v[64];

  if (job < 20) {
    int isq = (job < 16);
    int h = isq ? job : (job - 16);
    const float* src = isq ? (row + h * 64) : (row + NH_ * 64 + h * 64);
#pragma unroll
    for (int i = 0; i < 64; i += 4) {
      float4 f = *(const float4*)(src + i);
      v[i] = f.x; v[i + 1] = f.y; v[i + 2] = f.z; v[i + 3] = f.w;
    }
    const float* cs = cosT + t * 16;
    const float* sn = sinT + t * 16;
#pragma unroll
    for (int d = 0; d < 16; ++d) {
      float c = cs[d], s = sn[d];
      float a = v[d], bb = v[d + 16];
      v[d] = a * c - bb * s;
      v[d + 16] = a * s + bb * c;
    }
    float sc = isq ? (qk_scale[h] * (1.0f / 64.0f)) : 1.0f;
    unsigned short* dst = isq ? (qO + ((size_t)(b * NH_ + h) * T_ + t) * 64)
                              : (kO + ((size_t)(b * NKV_ + h) * T_ + t) * 64);
#pragma unroll
    for (int i = 0; i < 64; i += 8) {
      uint4 o;
      o.x = (unsigned)f2bf(v[i + 0] * sc) | ((unsigned)f2bf(v[i + 1] * sc) << 16);
      o.y = (unsigned)f2bf(v[i + 2] * sc) | ((unsigned)f2bf(v[i + 3] * sc) << 16);
      o.z = (unsigned)f2bf(v[i + 4] * sc) | ((unsigned)f2bf(v[i + 5] * sc) << 16);
      o.w = (unsigned)f2bf(v[i + 6] * sc) | ((unsigned)f2bf(v[i + 7] * sc) << 16);
      *(uint4*)(dst + i) = o;
    }
  } else {
    int h = job - 20;
    const float* src = row + (NH_ + NKV_) * 64 + (h >> 2) * 64;
    const float* v0p = v0 + ((size_t)(b * NH_ + h) * T_ + t) * 64;
    float a = 1.0f / (1.0f + __expf(-vrl_alpha[h]));
    float na = 1.0f - a;
    unsigned short* dst = vO + ((size_t)(b * NH_ + h) * T_ + t) * 64;
#pragma unroll
    for (int i = 0; i < 64; i += 4) {
      float4 f = *(const float4*)(src + i);
      float4 g = *(const float4*)(v0p + i);
      uint2 o;
      o.x = (unsigned)f2bf(na * f.x + a * g.x) | ((unsigned)f2bf(na * f.y + a * g.y) << 16);
      o.y = (unsigned)f2bf(na * f.z + a * g.z) | ((unsigned)f2bf(na * f.w + a * g.w) << 16);
      *(uint2*)(dst + i) = o;
    }
  }
}

// ---------------- flash attention, paired q-tiles + swapped QK^T ----------------
// grid (16, NH, B): block handles q-tiles qtA=p and qtB=31-p sharing staged K/V.
// 4 waves; wave w owns q rows [qt*64 + 16w, +16). Swapped S^T = mfma(K,Q): q lane-local.
__device__ __forceinline__ void stage_load(const unsigned short* Kb, const unsigned short* Vb,
                                           int kv0, int tid, uint4 kreg[2], uint4& ve, uint4& vo) {
#pragma unroll
  for (int i = 0; i < 2; ++i) {
    int cid = tid + i * 256;
    int r = cid >> 3, c = (cid & 7) * 8;
    kreg[i] = *(const uint4*)(Kb + (size_t)(kv0 + r) * 64 + c);
  }
  int kp = tid >> 3, cc = (tid & 7) * 8;
  ve = *(const uint4*)(Vb + (size_t)(kv0 + 2 * kp) * 64 + cc);
  vo = *(const uint4*)(Vb + (size_t)(kv0 + 2 * kp + 1) * 64 + cc);
}

__device__ __forceinline__ void stage_write(unsigned short (*KsB)[72], unsigned short (*VtB)[72],
                                            const uint4 kreg[2], uint4 ve, uint4 vo, int tid) {
#pragma unroll
  for (int i = 0; i < 2; ++i) {
    int cid = tid + i * 256;
    int r = cid >> 3, c = (cid & 7) * 8;
    *(uint4*)(&KsB[r][c]) = kreg[i];
  }
  int kp = tid >> 3, cc = (tid & 7) * 8;
  int skey = (2 * kp) ^ (8 * (cc >> 3));  // XOR swizzle spreads write banks
#pragma unroll
  for (int jj = 0; jj < 4; ++jj) {
    unsigned int e = ((const unsigned int*)&ve)[jj];
    unsigned int o = ((const unsigned int*)&vo)[jj];
    *(unsigned int*)(&VtB[cc + 2 * jj][skey])     = (e & 0xffffu) | (o << 16);
    *(unsigned int*)(&VtB[cc + 2 * jj + 1][skey]) = (e >> 16) | (o & 0xffff0000u);
  }
}

__device__ __forceinline__ void softmax_update(f32x4 (&s)[4], float& m, float& lsum, f32x4 (&y)[4],
                                               unsigned short* PsRow, int lo, int hi) {
  float pm = -INFINITY;
#pragma unroll
  for (int nt = 0; nt < 4; ++nt)
    pm = fmaxf(pm, fmaxf(fmaxf(s[nt][0], s[nt][1]), fmaxf(s[nt][2], s[nt][3])));
  pm = fmaxf(pm, __shfl_xor(pm, 16));
  pm = fmaxf(pm, __shfl_xor(pm, 32));
  float mnew = fmaxf(m, pm);
  float sc = __expf(m - mnew);  // first tile: exp(-inf)=0
  m = mnew;
  float rs = 0.f;
#pragma unroll
  for (int nt = 0; nt < 4; ++nt)
#pragma unroll
    for (int r = 0; r < 4; ++r) {
      float pv = __expf(s[nt][r] - mnew);
      s[nt][r] = pv;
      rs += pv;
    }
  rs += __shfl_xor(rs, 16);
  rs += __shfl_xor(rs, 32);
  lsum = lsum * sc + rs;
  // P[q=lo][k=nt*16+hi*4+r], packed 4 bf16 -> one b64 write
#pragma unroll
  for (int nt = 0; nt < 4; ++nt) {
    uint2 pk;
    pk.x = (unsigned)f2bf(s[nt][0]) | ((unsigned)f2bf(s[nt][1]) << 16);
    pk.y = (unsigned)f2bf(s[nt][2]) | ((unsigned)f2bf(s[nt][3]) << 16);
    *(uint2*)(PsRow + lo * 72 + nt * 16 + hi * 4) = pk;
  }
  // rescale y (rows q=hi*4+r): fetch sc of that q-row from lane hi*4+r
#pragma unroll
  for (int r = 0; r < 4; ++r) {
    float scr = __shfl(sc, hi * 4 + r);
#pragma unroll
    for (int nf = 0; nf < 4; ++nf) y[nf][r] *= scr;
  }
}

__global__ __launch_bounds__(256) void k_attn(const unsigned short* __restrict__ Q,
                                              const unsigned short* __restrict__ Kp,
                                              const unsigned short* __restrict__ Vp,
                                              unsigned short* __restrict__ Y) {
  int p = blockIdx.x, h = blockIdx.y, b = blockIdx.z;
  int tid = threadIdx.x;
  int w = tid >> 6, l = tid & 63, lo = l & 15, hi = l >> 4;
  int kh = h >> 2;
  int qtA = p, qtB = 31 - p;
  int ntB = qtB + 1;
  int q0A = qtA * 64 + w * 16, q0B = qtB * 64 + w * 16;

  __shared__ __align__(16) unsigned short Ks[2][64][72];
  __shared__ __align__(16) unsigned short Vt[2][64][72];
  __shared__ __align__(16) unsigned short Ps[2][4][16][72];

  const unsigned short* Qb = Q + ((size_t)(b * NH_ + h) * T_) * 64;
  const unsigned short* Kb = Kp + ((size_t)(b * NKV_ + kh) * T_) * 64;
  const unsigned short* Vb = Vp + ((size_t)(b * NH_ + h) * T_) * 64;

  bf16x8 qA0 = *(const bf16x8*)(Qb + (size_t)(q0A + lo) * 64 + hi * 8);
  bf16x8 qA1 = *(const bf16x8*)(Qb + (size_t)(q0A + lo) * 64 + 32 + hi * 8);
  bf16x8 qB0 = *(const bf16x8*)(Qb + (size_t)(q0B + lo) * 64 + hi * 8);
  bf16x8 qB1 = *(const bf16x8*)(Qb + (size_t)(q0B + lo) * 64 + 32 + hi * 8);

  f32x4 yA[4], yB[4];
#pragma unroll
  for (int nf = 0; nf < 4; ++nf) {
    yA[nf] = (f32x4){0.f, 0.f, 0.f, 0.f};
    yB[nf] = (f32x4){0.f, 0.f, 0.f, 0.f};
  }
  float mA = -INFINITY, lA = 0.f, mB = -INFINITY, lB = 0.f;

  uint4 kreg[2], ve, vo;
  stage_load(Kb, Vb, 0, tid, kreg, ve, vo);
  stage_write(Ks[0], Vt[0], kreg, ve, vo, tid);
  __syncthreads();
  int cur = 0;

  for (int kt = 0; kt < ntB; ++kt) {
    bool pf = (kt + 1) < ntB;
    if (pf) stage_load(Kb, Vb, (kt + 1) * 64, tid, kreg, ve, vo);
    bool actA = (kt <= qtA);
    int kv0 = kt * 64;

    // S^T = mfma(K, Q): D[key][q], q = lo, key = kv0 + nt*16 + hi*4 + r
    f32x4 sB[4], sA[4];
#pragma unroll
    for (int nt = 0; nt < 4; ++nt) {
      bf16x8 kf0 = *(const bf16x8*)&Ks[cur][nt * 16 + lo][hi * 8];
      bf16x8 kf1 = *(const bf16x8*)&Ks[cur][nt * 16 + lo][32 + hi * 8];
      f32x4 a = (f32x4){0.f, 0.f, 0.f, 0.f};
      a = __builtin_amdgcn_mfma_f32_16x16x32_bf16(kf0, qB0, a, 0, 0, 0);
      a = __builtin_amdgcn_mfma_f32_16x16x32_bf16(kf1, qB1, a, 0, 0, 0);
      sB[nt] = a;
      if (actA) {
        f32x4 aa = (f32x4){0.f, 0.f, 0.f, 0.f};
        aa = __builtin_amdgcn_mfma_f32_16x16x32_bf16(kf0, qA0, aa, 0, 0, 0);
        aa = __builtin_amdgcn_mfma_f32_16x16x32_bf16(kf1, qA1, aa, 0, 0, 0);
        sA[nt] = aa;
      }
    }

    if (kt == qtB) {  // diagonal for B
#pragma unroll
      for (int nt = 0; nt < 4; ++nt)
#pragma unroll
        for (int r = 0; r < 4; ++r)
          if (kv0 + nt * 16 + hi * 4 + r > q0B + lo) sB[nt][r] = -INFINITY;
    }
    if (actA && kt == qtA) {  // diagonal for A
#pragma unroll
      for (int nt = 0; nt < 4; ++nt)
#pragma unroll
        for (int r = 0; r < 4; ++r)
          if (kv0 + nt * 16 + hi * 4 + r > q0A + lo) sA[nt][r] = -INFINITY;
    }

    softmax_update(sB, mB, lB, yB, &Ps[0][w][0][0], lo, hi);
    if (actA) softmax_update(sA, mA, lA, yA, &Ps[1][w][0][0], lo, hi);

    // PV: y[q][d] += P[q][k] * V[k][d]; V frags shared across states
#pragma unroll
    for (int kc = 0; kc < 2; ++kc) {
      bf16x8 paB = *(const bf16x8*)&Ps[0][w][lo][kc * 32 + hi * 8];
      bf16x8 paA;
      if (actA) paA = *(const bf16x8*)&Ps[1][w][lo][kc * 32 + hi * 8];
#pragma unroll
      for (int nf = 0; nf < 4; ++nf) {
        int f = nf * 16 + lo;
        int kk = (kc * 32 + hi * 8) ^ (8 * ((f >> 3) & 7));
        bf16x8 vf = *(const bf16x8*)&Vt[cur][f][kk];
        yB[nf] = __builtin_amdgcn_mfma_f32_16x16x32_bf16(paB, vf, yB[nf], 0, 0, 0);
        if (actA) yA[nf] = __builtin_amdgcn_mfma_f32_16x16x32_bf16(paA, vf, yA[nf], 0, 0, 0);
      }
    }

    if (pf) stage_write(Ks[cur ^ 1], Vt[cur ^ 1], kreg, ve, vo, tid);
    __syncthreads();
    cur ^= 1;
  }

  // epilogue: divide by row sums; rows q=hi*4+r get l from lane hi*4+r
  float invA = 1.0f / lA, invB = 1.0f / lB;
#pragma unroll
  for (int r = 0; r < 4; ++r) {
    float iA = __shfl(invA, hi * 4 + r);
    float iB = __shfl(invB, hi * 4 + r);
    int tA = q0A + hi * 4 + r, tB = q0B + hi * 4 + r;
    unsigned short* ypA = Y + ((size_t)(b * T_ + tA)) * D_ + h * 64;
    unsigned short* ypB = Y + ((size_t)(b * T_ + tB)) * D_ + h * 64;
#pragma unroll
    for (int nf = 0; nf < 4; ++nf) {
      ypA[nf * 16 + lo] = f2bf(yA[nf][r] * iA);
      ypB[nf * 16 + lo] = f2bf(yB[nf][r] * iB);
    }
  }
}

extern "C" void kernel_launch(void* const* d_in, const int* in_sizes, int n_in,
                              void* d_out, int out_size, void* d_ws, size_t ws_size,
                              hipStream_t stream) {
  const float* x     = (const float*)d_in[0];
  const float* cosT  = (const float*)d_in[1];
  const float* sinT  = (const float*)d_in[2];
  const float* v0    = (const float*)d_in[3];
  const float* Wqkv  = (const float*)d_in[4];
  const float* Wproj = (const float*)d_in[5];
  const float* vrl   = (const float*)d_in[6];
  const float* qks   = (const float*)d_in[7];
  float* out = (float*)d_out;

  char* ws = (char*)d_ws;
  float*          qkv    = (float*)ws;                            // 25165824 B
  unsigned short* xb     = (unsigned short*)(ws + 25165824);      //  8388608 B
  unsigned short* wqkvb  = (unsigned short*)(ws + 33554432);      //  3145728 B
  unsigned short* wprojb = (unsigned short*)(ws + 36700160);      //  2097152 B
  unsigned short* qb     = (unsigned short*)(ws + 38797312);      //  8388608 B
  unsigned short* kb     = (unsigned short*)(ws + 47185920);      //  2097152 B
  unsigned short* vb     = (unsigned short*)(ws + 49283072);      //  8388608 B
  unsigned short* yb     = (unsigned short*)ws;                   // aliases qkv (dead by then)

  k_convert_all<<<3328, 256, 0, stream>>>(x, Wqkv, Wproj, xb, wqkvb, wprojb);

  k_gemm_bt<<<dim3(E_ / 128, (B_ * T_) / 128), 256, 0, stream>>>(xb, wqkvb, qkv, B_ * T_, E_, D_);

  k_transform<<<(B_ * T_ * 36) / 256, 256, 0, stream>>>(qkv, cosT, sinT, v0, vrl, qks, qb, kb, vb);

  k_attn<<<dim3(16, NH_, B_), 256, 0, stream>>>(qb, kb, vb, yb);

  k_gemm_bt<<<dim3(D_ / 128, (B_ * T_) / 128), 256, 0, stream>>>(yb, wprojb, out, B_ * T_, D_, D_);

  k_copy_f32<<<4194304 / 4 / 256, 256, 0, stream>>>((const float4*)v0, (float4*)(out + 4194304), 4194304 / 4);
}

// Round 3
// 152.497 us; speedup vs baseline: 1.7554x; 1.1588x over previous
//
#include <hip/hip_runtime.h>
#include <hip/hip_bf16.h>

#define B_   2
#define T_   2048
#define D_   1024
#define NH_  16
#define NKV_ 4
#define HD_  64
#define E_   1536  // (NH + 2*NKV) * HD
#define LOG2E 1.4426950408889634f

typedef __attribute__((ext_vector_type(8))) __bf16 bf16x8;
typedef __attribute__((ext_vector_type(4))) __bf16 bf16x4;
typedef __attribute__((ext_vector_type(4))) float f32x4;

// async global->LDS, 16B per lane. LDS dest = wave-uniform base + lane*16.
static __device__ __forceinline__ void gld_lds16(const unsigned short* g, unsigned short* l) {
  __builtin_amdgcn_global_load_lds(
      (const __attribute__((address_space(1))) unsigned int*)(unsigned long long)(const void*)g,
      (__attribute__((address_space(3))) unsigned int*)(unsigned int)(unsigned long long)(void*)l,
      16, 0, 0);
}

// ---------------- fused fp32 -> bf16 converts (8 elems/thread) ----------------
__global__ void k_convert_all(const float* __restrict__ x, const float* __restrict__ wq,
                              const float* __restrict__ wp, unsigned short* __restrict__ xb,
                              unsigned short* __restrict__ wqb, unsigned short* __restrict__ wpb) {
  int i = blockIdx.x * blockDim.x + threadIdx.x;
  const float* src; unsigned short* dst; int j;
  if (i < 524288)      { src = x;  dst = xb;  j = i; }
  else if (i < 720896) { src = wq; dst = wqb; j = i - 524288; }
  else                 { src = wp; dst = wpb; j = i - 720896; }
  const float4* p = (const float4*)src + (size_t)j * 2;
  float4 a = p[0], b = p[1];
  bf16x8 o;
  o[0] = (__bf16)a.x; o[1] = (__bf16)a.y; o[2] = (__bf16)a.z; o[3] = (__bf16)a.w;
  o[4] = (__bf16)b.x; o[5] = (__bf16)b.y; o[6] = (__bf16)b.z; o[7] = (__bf16)b.w;
  ((bf16x8*)dst)[j] = o;
}

// ---------------- float4 copy ----------------
__global__ void k_copy_f32(const float4* __restrict__ in, float4* __restrict__ out, int n4) {
  int i = blockIdx.x * blockDim.x + threadIdx.x;
  if (i < n4) out[i] = in[i];
}

// ---------------- QKV GEMM with fused RoPE/scale/V-mix epilogue ----------------
// C = x[4096,1024] * Wqkv[1536,1024]^T ; each wave's 64-col block = one head.
__global__ __launch_bounds__(256) void k_gemm_qkv(
    const unsigned short* __restrict__ A,
    const unsigned short* __restrict__ W,
    const float* __restrict__ cosT, const float* __restrict__ sinT,
    const float* __restrict__ v0,
    const float* __restrict__ vrl, const float* __restrict__ qks,
    unsigned short* __restrict__ qb, unsigned short* __restrict__ kb,
    unsigned short* __restrict__ vb) {
  __shared__ __align__(16) unsigned short As[128 * 32];
  __shared__ __align__(16) unsigned short Ws[128 * 32];
  int tid = threadIdx.x;
  int w = tid >> 6, l = tid & 63, lo = l & 15, hi = l >> 4;
  int wm = w >> 1, wn = w & 1;
  // XCD-aware swizzle (m204): nwg = 384, %8 == 0
  int gx = gridDim.x;
  int f = blockIdx.y * gx + blockIdx.x;
  int cpx = (gx * gridDim.y) >> 3;
  int f2 = (f & 7) * cpx + (f >> 3);
  int bn = f2 % gx, bm = f2 / gx;

  f32x4 acc[4][4];
#pragma unroll
  for (int i = 0; i < 4; ++i)
#pragma unroll
    for (int j = 0; j < 4; ++j) acc[i][j] = (f32x4){0.f, 0.f, 0.f, 0.f};

  const unsigned short* Ab = A + (size_t)bm * 128 * 1024;
  const unsigned short* Wb = W + (size_t)bn * 128 * 1024;
  int sr = l >> 2, sc4 = (l & 3) * 8;

  for (int k0 = 0; k0 < 1024; k0 += 32) {
#pragma unroll
    for (int i = 0; i < 2; ++i) {
      int rb = w * 32 + i * 16;
      gld_lds16(Ab + (size_t)(rb + sr) * 1024 + k0 + sc4, &As[rb * 32]);
      gld_lds16(Wb + (size_t)(rb + sr) * 1024 + k0 + sc4, &Ws[rb * 32]);
    }
    __syncthreads();
    bf16x8 af[4], wf[4];
#pragma unroll
    for (int mi = 0; mi < 4; ++mi) af[mi] = *(const bf16x8*)&As[(wm * 64 + mi * 16 + lo) * 32 + hi * 8];
#pragma unroll
    for (int ni = 0; ni < 4; ++ni) wf[ni] = *(const bf16x8*)&Ws[(wn * 64 + ni * 16 + lo) * 32 + hi * 8];
#pragma unroll
    for (int mi = 0; mi < 4; ++mi)
#pragma unroll
      for (int ni = 0; ni < 4; ++ni)
        acc[mi][ni] = __builtin_amdgcn_mfma_f32_16x16x32_bf16(af[mi], wf[ni], acc[mi][ni], 0, 0, 0);
    __syncthreads();
  }

  int hg = (bn * 128 + wn * 64) >> 6;  // wave-uniform head id: 0-15 q, 16-19 k, 20-23 v
  if (hg < 20) {
    int isq = (hg < 16);
    int h = isq ? hg : hg - 16;
    float sc = isq ? (qks[h] * (LOG2E / 64.0f)) : 1.0f;
    unsigned short* base = isq ? qb : kb;
    int nheads = isq ? NH_ : NKV_;
#pragma unroll
    for (int mi = 0; mi < 4; ++mi) {
#pragma unroll
      for (int r = 0; r < 4; ++r) {
        int row = bm * 128 + wm * 64 + mi * 16 + hi * 4 + r;
        int b = row >> 11, t = row & 2047;
        float c = cosT[t * 16 + lo], s = sinT[t * 16 + lo];
        float a0 = acc[mi][0][r], a1 = acc[mi][1][r];
        __bf16* dp = (__bf16*)(base + ((size_t)(b * nheads + h) * T_ + t) * 64);
        dp[lo]      = (__bf16)((a0 * c - a1 * s) * sc);
        dp[16 + lo] = (__bf16)((a0 * s + a1 * c) * sc);
        dp[32 + lo] = (__bf16)(acc[mi][2][r] * sc);
        dp[48 + lo] = (__bf16)(acc[mi][3][r] * sc);
      }
    }
  } else {
    int hv = hg - 20;
    float av[4];
#pragma unroll
    for (int j = 0; j < 4; ++j) av[j] = 1.0f / (1.0f + __expf(-vrl[hv * 4 + j]));
#pragma unroll
    for (int mi = 0; mi < 4; ++mi) {
#pragma unroll
      for (int r = 0; r < 4; ++r) {
        int row = bm * 128 + wm * 64 + mi * 16 + hi * 4 + r;
        int b = row >> 11, t = row & 2047;
#pragma unroll
        for (int ni = 0; ni < 4; ++ni) {
          int d = ni * 16 + lo;
          float vv = acc[mi][ni][r];
#pragma unroll
          for (int j = 0; j < 4; ++j) {
            size_t idx = ((size_t)(b * NH_ + hv * 4 + j) * T_ + t) * 64 + d;
            ((__bf16*)vb)[idx] = (__bf16)((1.0f - av[j]) * vv + av[j] * v0[idx]);
          }
        }
      }
    }
  }
}

// ---------------- proj GEMM: C[M,N] = A[M,K]*W[N,K]^T, bf16 in fp32 out ----------
__global__ __launch_bounds__(256) void k_gemm_bt(
    const unsigned short* __restrict__ A,
    const unsigned short* __restrict__ W,
    float* __restrict__ C, int M, int N, int K) {
  __shared__ __align__(16) unsigned short As[128 * 32];
  __shared__ __align__(16) unsigned short Ws[128 * 32];
  int tid = threadIdx.x;
  int w = tid >> 6, l = tid & 63, lo = l & 15, hi = l >> 4;
  int wm = w >> 1, wn = w & 1;
  int gx = gridDim.x;
  int f = blockIdx.y * gx + blockIdx.x;
  int cpx = (gx * gridDim.y) >> 3;
  int f2 = (f & 7) * cpx + (f >> 3);
  int bn = f2 % gx, bm = f2 / gx;

  f32x4 acc[4][4];
#pragma unroll
  for (int i = 0; i < 4; ++i)
#pragma unroll
    for (int j = 0; j < 4; ++j) acc[i][j] = (f32x4){0.f, 0.f, 0.f, 0.f};

  const unsigned short* Ab = A + (size_t)bm * 128 * K;
  const unsigned short* Wb = W + (size_t)bn * 128 * K;
  int sr = l >> 2, sc = (l & 3) * 8;

  for (int k0 = 0; k0 < K; k0 += 32) {
#pragma unroll
    for (int i = 0; i < 2; ++i) {
      int rb = w * 32 + i * 16;
      gld_lds16(Ab + (size_t)(rb + sr) * K + k0 + sc, &As[rb * 32]);
      gld_lds16(Wb + (size_t)(rb + sr) * K + k0 + sc, &Ws[rb * 32]);
    }
    __syncthreads();
    bf16x8 af[4], wf[4];
#pragma unroll
    for (int mi = 0; mi < 4; ++mi) af[mi] = *(const bf16x8*)&As[(wm * 64 + mi * 16 + lo) * 32 + hi * 8];
#pragma unroll
    for (int ni = 0; ni < 4; ++ni) wf[ni] = *(const bf16x8*)&Ws[(wn * 64 + ni * 16 + lo) * 32 + hi * 8];
#pragma unroll
    for (int mi = 0; mi < 4; ++mi)
#pragma unroll
      for (int ni = 0; ni < 4; ++ni)
        acc[mi][ni] = __builtin_amdgcn_mfma_f32_16x16x32_bf16(af[mi], wf[ni], acc[mi][ni], 0, 0, 0);
    __syncthreads();
  }

#pragma unroll
  for (int mi = 0; mi < 4; ++mi) {
#pragma unroll
    for (int r = 0; r < 4; ++r) {
      int row = bm * 128 + wm * 64 + mi * 16 + hi * 4 + r;
      float* cp = C + (size_t)row * N + bn * 128 + wn * 64 + lo;
#pragma unroll
      for (int ni = 0; ni < 4; ++ni) cp[ni * 16] = acc[mi][ni][r];
    }
  }
}

// ---------------- flash attention (exp2 domain, defer-max, paired q-tiles) --------------
__device__ __forceinline__ void stage_load(const unsigned short* Kb, const unsigned short* Vb,
                                           int kv0, int tid, uint4 kreg[2], uint4& ve, uint4& vo) {
#pragma unroll
  for (int i = 0; i < 2; ++i) {
    int cid = tid + i * 256;
    int r = cid >> 3, c = (cid & 7) * 8;
    kreg[i] = *(const uint4*)(Kb + (size_t)(kv0 + r) * 64 + c);
  }
  int kp = tid >> 3, cc = (tid & 7) * 8;
  ve = *(const uint4*)(Vb + (size_t)(kv0 + 2 * kp) * 64 + cc);
  vo = *(const uint4*)(Vb + (size_t)(kv0 + 2 * kp + 1) * 64 + cc);
}

__device__ __forceinline__ void stage_write(unsigned short (*KsB)[72], unsigned short (*VtB)[72],
                                            const uint4 kreg[2], uint4 ve, uint4 vo, int tid) {
#pragma unroll
  for (int i = 0; i < 2; ++i) {
    int cid = tid + i * 256;
    int r = cid >> 3, c = (cid & 7) * 8;
    *(uint4*)(&KsB[r][c]) = kreg[i];
  }
  int kp = tid >> 3, cc = (tid & 7) * 8;
  int skey = (2 * kp) ^ (8 * (cc >> 3));  // XOR swizzle spreads write banks
#pragma unroll
  for (int jj = 0; jj < 4; ++jj) {
    unsigned int e = ((const unsigned int*)&ve)[jj];
    unsigned int o = ((const unsigned int*)&vo)[jj];
    *(unsigned int*)(&VtB[cc + 2 * jj][skey])     = (e & 0xffffu) | (o << 16);
    *(unsigned int*)(&VtB[cc + 2 * jj + 1][skey]) = (e >> 16) | (o & 0xffff0000u);
  }
}

// online softmax in exp2 domain, defer-max (THR=8), per-lane partial lsum
__device__ __forceinline__ void softmax_state(f32x4 (&s)[4], float& m, float& lsum,
                                              f32x4 (&y)[4], unsigned short* PsRow,
                                              int lo, int hi) {
  float m01 = fmaxf(fmaxf(s[0][0], s[0][1]), fmaxf(s[0][2], s[0][3]));
  float m23 = fmaxf(fmaxf(s[1][0], s[1][1]), fmaxf(s[1][2], s[1][3]));
  float m45 = fmaxf(fmaxf(s[2][0], s[2][1]), fmaxf(s[2][2], s[2][3]));
  float m67 = fmaxf(fmaxf(s[3][0], s[3][1]), fmaxf(s[3][2], s[3][3]));
  float pm = fmaxf(fmaxf(m01, m23), fmaxf(m45, m67));
  if (!__all(pm <= m + 8.0f)) {  // rare after first tile
    pm = fmaxf(pm, __shfl_xor(pm, 16));
    pm = fmaxf(pm, __shfl_xor(pm, 32));
    float mnew = fmaxf(m, pm);
    float sc = exp2f(m - mnew);
    lsum *= sc;
#pragma unroll
    for (int r = 0; r < 4; ++r) {
      float scr = __shfl(sc, hi * 4 + r);
#pragma unroll
      for (int nf = 0; nf < 4; ++nf) y[nf][r] *= scr;
    }
    m = mnew;
  }
  float rs = 0.f;
#pragma unroll
  for (int nt = 0; nt < 4; ++nt) {
    float p0 = exp2f(s[nt][0] - m);
    float p1 = exp2f(s[nt][1] - m);
    float p2 = exp2f(s[nt][2] - m);
    float p3 = exp2f(s[nt][3] - m);
    rs += (p0 + p1) + (p2 + p3);
    bf16x4 pk;
    pk[0] = (__bf16)p0; pk[1] = (__bf16)p1; pk[2] = (__bf16)p2; pk[3] = (__bf16)p3;
    *(bf16x4*)(PsRow + lo * 72 + nt * 16 + hi * 4) = pk;
  }
  lsum += rs;
}

__global__ __launch_bounds__(256) void k_attn(const unsigned short* __restrict__ Q,
                                              const unsigned short* __restrict__ Kp,
                                              const unsigned short* __restrict__ Vp,
                                              unsigned short* __restrict__ Y) {
  int p = blockIdx.x, h = blockIdx.y, b = blockIdx.z;
  int tid = threadIdx.x;
  int w = tid >> 6, l = tid & 63, lo = l & 15, hi = l >> 4;
  int kh = h >> 2;
  int qtA = p, qtB = 31 - p;
  int ntB = qtB + 1;
  int q0A = qtA * 64 + w * 16, q0B = qtB * 64 + w * 16;

  __shared__ __align__(16) unsigned short Ks[2][64][72];
  __shared__ __align__(16) unsigned short Vt[2][64][72];
  __shared__ __align__(16) unsigned short Ps[2][4][16][72];

  const unsigned short* Qb = Q + ((size_t)(b * NH_ + h) * T_) * 64;
  const unsigned short* Kb = Kp + ((size_t)(b * NKV_ + kh) * T_) * 64;
  const unsigned short* Vb = Vp + ((size_t)(b * NH_ + h) * T_) * 64;

  bf16x8 qA0 = *(const bf16x8*)(Qb + (size_t)(q0A + lo) * 64 + hi * 8);
  bf16x8 qA1 = *(const bf16x8*)(Qb + (size_t)(q0A + lo) * 64 + 32 + hi * 8);
  bf16x8 qB0 = *(const bf16x8*)(Qb + (size_t)(q0B + lo) * 64 + hi * 8);
  bf16x8 qB1 = *(const bf16x8*)(Qb + (size_t)(q0B + lo) * 64 + 32 + hi * 8);

  f32x4 yA[4], yB[4];
#pragma unroll
  for (int nf = 0; nf < 4; ++nf) {
    yA[nf] = (f32x4){0.f, 0.f, 0.f, 0.f};
    yB[nf] = (f32x4){0.f, 0.f, 0.f, 0.f};
  }
  float mA = -INFINITY, lA = 0.f, mB = -INFINITY, lB = 0.f;

  uint4 kreg[2], ve, vo;
  stage_load(Kb, Vb, 0, tid, kreg, ve, vo);
  stage_write(Ks[0], Vt[0], kreg, ve, vo, tid);
  __syncthreads();
  int cur = 0;

  for (int kt = 0; kt < ntB; ++kt) {
    bool pf = (kt + 1) < ntB;
    if (pf) stage_load(Kb, Vb, (kt + 1) * 64, tid, kreg, ve, vo);
    bool actA = (kt <= qtA);
    int kv0 = kt * 64;

    // S^T = mfma(K, Q): D[key][q], q = lo, key = kv0 + nt*16 + hi*4 + r
    f32x4 sB[4], sA[4];
    __builtin_amdgcn_s_setprio(1);
#pragma unroll
    for (int nt = 0; nt < 4; ++nt) {
      bf16x8 kf0 = *(const bf16x8*)&Ks[cur][nt * 16 + lo][hi * 8];
      bf16x8 kf1 = *(const bf16x8*)&Ks[cur][nt * 16 + lo][32 + hi * 8];
      f32x4 a = (f32x4){0.f, 0.f, 0.f, 0.f};
      a = __builtin_amdgcn_mfma_f32_16x16x32_bf16(kf0, qB0, a, 0, 0, 0);
      a = __builtin_amdgcn_mfma_f32_16x16x32_bf16(kf1, qB1, a, 0, 0, 0);
      sB[nt] = a;
      if (actA) {
        f32x4 aa = (f32x4){0.f, 0.f, 0.f, 0.f};
        aa = __builtin_amdgcn_mfma_f32_16x16x32_bf16(kf0, qA0, aa, 0, 0, 0);
        aa = __builtin_amdgcn_mfma_f32_16x16x32_bf16(kf1, qA1, aa, 0, 0, 0);
        sA[nt] = aa;
      }
    }
    __builtin_amdgcn_s_setprio(0);

    if (kt == qtB) {
#pragma unroll
      for (int nt = 0; nt < 4; ++nt)
#pragma unroll
        for (int r = 0; r < 4; ++r)
          if (kv0 + nt * 16 + hi * 4 + r > q0B + lo) sB[nt][r] = -1e30f;
    }
    if (actA && kt == qtA) {
#pragma unroll
      for (int nt = 0; nt < 4; ++nt)
#pragma unroll
        for (int r = 0; r < 4; ++r)
          if (kv0 + nt * 16 + hi * 4 + r > q0A + lo) sA[nt][r] = -1e30f;
    }

    softmax_state(sB, mB, lB, yB, &Ps[0][w][0][0], lo, hi);
    if (actA) softmax_state(sA, mA, lA, yA, &Ps[1][w][0][0], lo, hi);

    // PV: y[q][d] += P[q][k] * V[k][d]; V frags shared across states
    __builtin_amdgcn_s_setprio(1);
#pragma unroll
    for (int kc = 0; kc < 2; ++kc) {
      bf16x8 paB = *(const bf16x8*)&Ps[0][w][lo][kc * 32 + hi * 8];
      bf16x8 paA;
      if (actA) paA = *(const bf16x8*)&Ps[1][w][lo][kc * 32 + hi * 8];
#pragma unroll
      for (int nf = 0; nf < 4; ++nf) {
        int fq = nf * 16 + lo;
        int kk = (kc * 32 + hi * 8) ^ (8 * ((fq >> 3) & 7));
        bf16x8 vf = *(const bf16x8*)&Vt[cur][fq][kk];
        yB[nf] = __builtin_amdgcn_mfma_f32_16x16x32_bf16(paB, vf, yB[nf], 0, 0, 0);
        if (actA) yA[nf] = __builtin_amdgcn_mfma_f32_16x16x32_bf16(paA, vf, yA[nf], 0, 0, 0);
      }
    }
    __builtin_amdgcn_s_setprio(0);

    if (pf) stage_write(Ks[cur ^ 1], Vt[cur ^ 1], kreg, ve, vo, tid);
    __syncthreads();
    cur ^= 1;
  }

  // epilogue: reduce per-lane partial sums, divide, store
  lA += __shfl_xor(lA, 16); lA += __shfl_xor(lA, 32);
  lB += __shfl_xor(lB, 16); lB += __shfl_xor(lB, 32);
  float invA = 1.0f / lA, invB = 1.0f / lB;
#pragma unroll
  for (int r = 0; r < 4; ++r) {
    float iA = __shfl(invA, hi * 4 + r);
    float iB = __shfl(invB, hi * 4 + r);
    int tA = q0A + hi * 4 + r, tB = q0B + hi * 4 + r;
    __bf16* ypA = (__bf16*)(Y + ((size_t)(b * T_ + tA)) * D_ + h * 64);
    __bf16* ypB = (__bf16*)(Y + ((size_t)(b * T_ + tB)) * D_ + h * 64);
#pragma unroll
    for (int nf = 0; nf < 4; ++nf) {
      ypA[nf * 16 + lo] = (__bf16)(yA[nf][r] * iA);
      ypB[nf * 16 + lo] = (__bf16)(yB[nf][r] * iB);
    }
  }
}

extern "C" void kernel_launch(void* const* d_in, const int* in_sizes, int n_in,
                              void* d_out, int out_size, void* d_ws, size_t ws_size,
                              hipStream_t stream) {
  const float* x     = (const float*)d_in[0];
  const float* cosT  = (const float*)d_in[1];
  const float* sinT  = (const float*)d_in[2];
  const float* v0    = (const float*)d_in[3];
  const float* Wqkv  = (const float*)d_in[4];
  const float* Wproj = (const float*)d_in[5];
  const float* vrl   = (const float*)d_in[6];
  const float* qks   = (const float*)d_in[7];
  float* out = (float*)d_out;

  char* ws = (char*)d_ws;
  unsigned short* xb     = (unsigned short*)ws;                   //  8388608 B
  unsigned short* wqkvb  = (unsigned short*)(ws + 8388608);       //  3145728 B
  unsigned short* wprojb = (unsigned short*)(ws + 11534336);      //  2097152 B
  unsigned short* qb     = (unsigned short*)(ws + 13631488);      //  8388608 B
  unsigned short* kb     = (unsigned short*)(ws + 22020096);      //  2097152 B
  unsigned short* vb     = (unsigned short*)(ws + 24117248);      //  8388608 B
  unsigned short* yb     = (unsigned short*)(ws + 32505856);      //  8388608 B

  k_convert_all<<<3328, 256, 0, stream>>>(x, Wqkv, Wproj, xb, wqkvb, wprojb);

  k_gemm_qkv<<<dim3(E_ / 128, (B_ * T_) / 128), 256, 0, stream>>>(
      xb, wqkvb, cosT, sinT, v0, vrl, qks, qb, kb, vb);

  k_attn<<<dim3(16, NH_, B_), 256, 0, stream>>>(qb, kb, vb, yb);

  k_gemm_bt<<<dim3(D_ / 128, (B_ * T_) / 128), 256, 0, stream>>>(yb, wprojb, out, B_ * T_, D_, D_);

  k_copy_f32<<<4194304 / 4 / 256, 256, 0, stream>>>((const float4*)v0, (float4*)(out + 4194304), 4194304 / 4);
}

// Round 4
// 142.590 us; speedup vs baseline: 1.8774x; 1.0695x over previous
//
#include <hip/hip_runtime.h>
#include <hip/hip_bf16.h>

#define B_   2
#define T_   2048
#define D_   1024
#define NH_  16
#define NKV_ 4
#define HD_  64
#define E_   1536  // (NH + 2*NKV) * HD
#define LOG2E 1.4426950408889634f

typedef __attribute__((ext_vector_type(8))) __bf16 bf16x8;
typedef __attribute__((ext_vector_type(4))) __bf16 bf16x4;
typedef __attribute__((ext_vector_type(4))) float f32x4;

// async global->LDS, 16B per lane. LDS dest = wave-uniform base + lane*16.
static __device__ __forceinline__ void gld_lds16(const unsigned short* g, unsigned short* l) {
  __builtin_amdgcn_global_load_lds(
      (const __attribute__((address_space(1))) unsigned int*)(unsigned long long)(const void*)g,
      (__attribute__((address_space(3))) unsigned int*)(unsigned int)(unsigned long long)(void*)l,
      16, 0, 0);
}

// ------------- fused fp32->bf16 converts + v0 passthrough copy -------------
__global__ void k_convert_all(const float* __restrict__ x, const float* __restrict__ wq,
                              const float* __restrict__ wp, const float* __restrict__ v0,
                              unsigned short* __restrict__ xb, unsigned short* __restrict__ wqb,
                              unsigned short* __restrict__ wpb, float* __restrict__ out2) {
  int i = blockIdx.x * blockDim.x + threadIdx.x;
  if (i < 851968) {
    const float* src; unsigned short* dst; int j;
    if (i < 524288)      { src = x;  dst = xb;  j = i; }
    else if (i < 720896) { src = wq; dst = wqb; j = i - 524288; }
    else                 { src = wp; dst = wpb; j = i - 720896; }
    const float4* p = (const float4*)src + (size_t)j * 2;
    float4 a = p[0], b = p[1];
    bf16x8 o;
    o[0] = (__bf16)a.x; o[1] = (__bf16)a.y; o[2] = (__bf16)a.z; o[3] = (__bf16)a.w;
    o[4] = (__bf16)b.x; o[5] = (__bf16)b.y; o[6] = (__bf16)b.z; o[7] = (__bf16)b.w;
    ((bf16x8*)dst)[j] = o;
  } else {
    int j = i - 851968;  // 524288 copy units of 8 floats
    const float4* p = (const float4*)v0 + (size_t)j * 2;
    float4* q = (float4*)out2 + (size_t)j * 2;
    q[0] = p[0]; q[1] = p[1];
  }
}

// ---------------- QKV GEMM with fused RoPE/scale/V-mix epilogue ----------------
// q: linear [b][h][t][d]; k: [b][kh][t][d ^ 8*(t&7)]; v_eff: [b][h][d][t ^ 8*(d&7) in 64-blk]
__global__ __launch_bounds__(256) void k_gemm_qkv(
    const unsigned short* __restrict__ A,
    const unsigned short* __restrict__ W,
    const float* __restrict__ cosT, const float* __restrict__ sinT,
    const float* __restrict__ v0,
    const float* __restrict__ vrl, const float* __restrict__ qks,
    unsigned short* __restrict__ qb, unsigned short* __restrict__ kb,
    unsigned short* __restrict__ vb) {
  __shared__ __align__(16) unsigned short As[128 * 32];
  __shared__ __align__(16) unsigned short Ws[128 * 32];
  int tid = threadIdx.x;
  int w = tid >> 6, l = tid & 63, lo = l & 15, hi = l >> 4;
  int wm = w >> 1, wn = w & 1;
  int gx = gridDim.x;
  int f = blockIdx.y * gx + blockIdx.x;
  int cpx = (gx * gridDim.y) >> 3;
  int f2 = (f & 7) * cpx + (f >> 3);
  int bn = f2 % gx, bm = f2 / gx;

  f32x4 acc[4][4];
#pragma unroll
  for (int i = 0; i < 4; ++i)
#pragma unroll
    for (int j = 0; j < 4; ++j) acc[i][j] = (f32x4){0.f, 0.f, 0.f, 0.f};

  const unsigned short* Ab = A + (size_t)bm * 128 * 1024;
  const unsigned short* Wb = W + (size_t)bn * 128 * 1024;
  int sr = l >> 2, sc4 = (l & 3) * 8;

  for (int k0 = 0; k0 < 1024; k0 += 32) {
#pragma unroll
    for (int i = 0; i < 2; ++i) {
      int rb = w * 32 + i * 16;
      gld_lds16(Ab + (size_t)(rb + sr) * 1024 + k0 + sc4, &As[rb * 32]);
      gld_lds16(Wb + (size_t)(rb + sr) * 1024 + k0 + sc4, &Ws[rb * 32]);
    }
    __syncthreads();
    bf16x8 af[4], wf[4];
#pragma unroll
    for (int mi = 0; mi < 4; ++mi) af[mi] = *(const bf16x8*)&As[(wm * 64 + mi * 16 + lo) * 32 + hi * 8];
#pragma unroll
    for (int ni = 0; ni < 4; ++ni) wf[ni] = *(const bf16x8*)&Ws[(wn * 64 + ni * 16 + lo) * 32 + hi * 8];
#pragma unroll
    for (int mi = 0; mi < 4; ++mi)
#pragma unroll
      for (int ni = 0; ni < 4; ++ni)
        acc[mi][ni] = __builtin_amdgcn_mfma_f32_16x16x32_bf16(af[mi], wf[ni], acc[mi][ni], 0, 0, 0);
    __syncthreads();
  }

  int hg = (bn * 128 + wn * 64) >> 6;  // 0-15 q, 16-19 k, 20-23 v
  if (hg < 20) {
    int isq = (hg < 16);
    int h = isq ? hg : hg - 16;
    float sc = isq ? (qks[h] * (LOG2E / 64.0f)) : 1.0f;
    unsigned short* base = isq ? qb : kb;
    int nheads = isq ? NH_ : NKV_;
#pragma unroll
    for (int mi = 0; mi < 4; ++mi) {
#pragma unroll
      for (int r = 0; r < 4; ++r) {
        int row = bm * 128 + wm * 64 + mi * 16 + hi * 4 + r;
        int b = row >> 11, t = row & 2047;
        float c = cosT[t * 16 + lo], s = sinT[t * 16 + lo];
        float a0 = acc[mi][0][r], a1 = acc[mi][1][r];
        __bf16* dp = (__bf16*)(base + ((size_t)(b * nheads + h) * T_ + t) * 64);
        int ts = isq ? 0 : (8 * (t & 7));  // K stored with d-swizzle for LDS bank spread
        dp[lo ^ ts]        = (__bf16)((a0 * c - a1 * s) * sc);
        dp[(16 + lo) ^ ts] = (__bf16)((a0 * s + a1 * c) * sc);
        dp[(32 + lo) ^ ts] = (__bf16)(acc[mi][2][r] * sc);
        dp[(48 + lo) ^ ts] = (__bf16)(acc[mi][3][r] * sc);
      }
    }
  } else {
    int hv = hg - 20;
    float av[4];
#pragma unroll
    for (int j = 0; j < 4; ++j) av[j] = 1.0f / (1.0f + __expf(-vrl[hv * 4 + j]));
    int d = 0;
#pragma unroll
    for (int mi = 0; mi < 4; ++mi) {
      int t0g = bm * 128 + wm * 64 + mi * 16 + hi * 4;
      int b = t0g >> 11, t0 = t0g & 2047;
#pragma unroll
      for (int ni = 0; ni < 4; ++ni) {
        d = ni * 16 + lo;
#pragma unroll
        for (int j = 0; j < 4; ++j) {
          float a = av[j], na = 1.0f - a;
          const float* v0p = v0 + ((size_t)(b * NH_ + hv * 4 + j) * T_ + t0) * 64 + d;
          bf16x4 vv;
#pragma unroll
          for (int r = 0; r < 4; ++r)
            vv[r] = (__bf16)(na * acc[mi][ni][r] + a * v0p[(size_t)r * 64]);
          // v^T store: [b][h][d][t], t swizzled within its 64-block by 8*(d&7)
          *(bf16x4*)((unsigned short*)vb + ((size_t)(b * NH_ + hv * 4 + j) * 64 + d) * T_ +
                     (t0 ^ (8 * (lo & 7)))) = vv;
        }
      }
    }
  }
}

// ---------------- proj GEMM: C[M,N] = A[M,K]*W[N,K]^T, bf16 in fp32 out ----------
__global__ __launch_bounds__(256) void k_gemm_bt(
    const unsigned short* __restrict__ A,
    const unsigned short* __restrict__ W,
    float* __restrict__ C, int M, int N, int K) {
  __shared__ __align__(16) unsigned short As[128 * 32];
  __shared__ __align__(16) unsigned short Ws[128 * 32];
  int tid = threadIdx.x;
  int w = tid >> 6, l = tid & 63, lo = l & 15, hi = l >> 4;
  int wm = w >> 1, wn = w & 1;
  int gx = gridDim.x;
  int f = blockIdx.y * gx + blockIdx.x;
  int cpx = (gx * gridDim.y) >> 3;
  int f2 = (f & 7) * cpx + (f >> 3);
  int bn = f2 % gx, bm = f2 / gx;

  f32x4 acc[4][4];
#pragma unroll
  for (int i = 0; i < 4; ++i)
#pragma unroll
    for (int j = 0; j < 4; ++j) acc[i][j] = (f32x4){0.f, 0.f, 0.f, 0.f};

  const unsigned short* Ab = A + (size_t)bm * 128 * K;
  const unsigned short* Wb = W + (size_t)bn * 128 * K;
  int sr = l >> 2, sc = (l & 3) * 8;

  for (int k0 = 0; k0 < K; k0 += 32) {
#pragma unroll
    for (int i = 0; i < 2; ++i) {
      int rb = w * 32 + i * 16;
      gld_lds16(Ab + (size_t)(rb + sr) * K + k0 + sc, &As[rb * 32]);
      gld_lds16(Wb + (size_t)(rb + sr) * K + k0 + sc, &Ws[rb * 32]);
    }
    __syncthreads();
    bf16x8 af[4], wf[4];
#pragma unroll
    for (int mi = 0; mi < 4; ++mi) af[mi] = *(const bf16x8*)&As[(wm * 64 + mi * 16 + lo) * 32 + hi * 8];
#pragma unroll
    for (int ni = 0; ni < 4; ++ni) wf[ni] = *(const bf16x8*)&Ws[(wn * 64 + ni * 16 + lo) * 32 + hi * 8];
#pragma unroll
    for (int mi = 0; mi < 4; ++mi)
#pragma unroll
      for (int ni = 0; ni < 4; ++ni)
        acc[mi][ni] = __builtin_amdgcn_mfma_f32_16x16x32_bf16(af[mi], wf[ni], acc[mi][ni], 0, 0, 0);
    __syncthreads();
  }

#pragma unroll
  for (int mi = 0; mi < 4; ++mi) {
#pragma unroll
    for (int r = 0; r < 4; ++r) {
      int row = bm * 128 + wm * 64 + mi * 16 + hi * 4 + r;
      float* cp = C + (size_t)row * N + bn * 128 + wn * 64 + lo;
#pragma unroll
      for (int ni = 0; ni < 4; ++ni) cp[ni * 16] = acc[mi][ni][r];
    }
  }
}

// ---------------- flash attention: gld_lds staging, swizzled LDS, paired q-tiles ---------
static __device__ __forceinline__ void stage_kv(const unsigned short* Kb, const unsigned short* Vb,
                                                int kv0, int w, int l,
                                                unsigned short* KsB, unsigned short* VsB) {
#pragma unroll
  for (int i = 0; i < 2; ++i) {
    int ch = w + 4 * i;  // 1KB chunk id, 8 chunks per 8KB tile
    gld_lds16(Kb + (size_t)kv0 * 64 + ch * 512 + l * 8, KsB + ch * 512);
    gld_lds16(Vb + (size_t)(ch * 8 + (l >> 3)) * T_ + kv0 + (l & 7) * 8, VsB + ch * 512);
  }
}

// online softmax in exp2 domain, defer-max (THR=8), per-lane partial lsum
__device__ __forceinline__ void softmax_state(f32x4 (&s)[4], float& m, float& lsum,
                                              f32x4 (&y)[4], unsigned short* PsW,
                                              int lo, int hi, int swz) {
  float m01 = fmaxf(fmaxf(s[0][0], s[0][1]), fmaxf(s[0][2], s[0][3]));
  float m23 = fmaxf(fmaxf(s[1][0], s[1][1]), fmaxf(s[1][2], s[1][3]));
  float m45 = fmaxf(fmaxf(s[2][0], s[2][1]), fmaxf(s[2][2], s[2][3]));
  float m67 = fmaxf(fmaxf(s[3][0], s[3][1]), fmaxf(s[3][2], s[3][3]));
  float pm = fmaxf(fmaxf(m01, m23), fmaxf(m45, m67));
  if (!__all(pm <= m + 8.0f)) {  // rare after first tile
    pm = fmaxf(pm, __shfl_xor(pm, 16));
    pm = fmaxf(pm, __shfl_xor(pm, 32));
    float mnew = fmaxf(m, pm);
    float sc = exp2f(m - mnew);
    lsum *= sc;
#pragma unroll
    for (int r = 0; r < 4; ++r) {
      float scr = __shfl(sc, hi * 4 + r);
#pragma unroll
      for (int nf = 0; nf < 4; ++nf) y[nf][r] *= scr;
    }
    m = mnew;
  }
  float rs = 0.f;
#pragma unroll
  for (int nt = 0; nt < 4; ++nt) {
    float p0 = exp2f(s[nt][0] - m);
    float p1 = exp2f(s[nt][1] - m);
    float p2 = exp2f(s[nt][2] - m);
    float p3 = exp2f(s[nt][3] - m);
    rs += (p0 + p1) + (p2 + p3);
    bf16x4 pk;
    pk[0] = (__bf16)p0; pk[1] = (__bf16)p1; pk[2] = (__bf16)p2; pk[3] = (__bf16)p3;
    *(bf16x4*)(PsW + lo * 64 + ((nt * 16 + hi * 4) ^ swz)) = pk;
  }
  lsum += rs;
}

__global__ __launch_bounds__(256) void k_attn(const unsigned short* __restrict__ Q,
                                              const unsigned short* __restrict__ Kp,
                                              const unsigned short* __restrict__ Vtp,
                                              unsigned short* __restrict__ Y) {
  int p = blockIdx.x, h = blockIdx.y, b = blockIdx.z;
  int tid = threadIdx.x;
  int w = tid >> 6, l = tid & 63, lo = l & 15, hi = l >> 4;
  int kh = h >> 2;
  int qtA = p, qtB = 31 - p;
  int ntB = qtB + 1;
  int q0A = qtA * 64 + w * 16, q0B = qtB * 64 + w * 16;
  int swz = 8 * (lo & 7);

  __shared__ __align__(16) unsigned short Ks[2][4096];
  __shared__ __align__(16) unsigned short Vs[2][4096];
  __shared__ __align__(16) unsigned short Ps[2][4096];  // [state][w*1024 + row*64 + col]

  const unsigned short* Qb = Q + ((size_t)(b * NH_ + h) * T_) * 64;
  const unsigned short* Kb = Kp + ((size_t)(b * NKV_ + kh) * T_) * 64;
  const unsigned short* Vb = Vtp + ((size_t)(b * NH_ + h) * 64) * T_;

  bf16x8 qA0 = *(const bf16x8*)(Qb + (size_t)(q0A + lo) * 64 + hi * 8);
  bf16x8 qA1 = *(const bf16x8*)(Qb + (size_t)(q0A + lo) * 64 + 32 + hi * 8);
  bf16x8 qB0 = *(const bf16x8*)(Qb + (size_t)(q0B + lo) * 64 + hi * 8);
  bf16x8 qB1 = *(const bf16x8*)(Qb + (size_t)(q0B + lo) * 64 + 32 + hi * 8);

  f32x4 yA[4], yB[4];
#pragma unroll
  for (int nf = 0; nf < 4; ++nf) {
    yA[nf] = (f32x4){0.f, 0.f, 0.f, 0.f};
    yB[nf] = (f32x4){0.f, 0.f, 0.f, 0.f};
  }
  float mA = -INFINITY, lA = 0.f, mB = -INFINITY, lB = 0.f;

  stage_kv(Kb, Vb, 0, w, l, Ks[0], Vs[0]);
  __syncthreads();
  int cur = 0;

  for (int kt = 0; kt < ntB; ++kt) {
    bool pf = (kt + 1) < ntB;
    if (pf) stage_kv(Kb, Vb, (kt + 1) * 64, w, l, Ks[cur ^ 1], Vs[cur ^ 1]);
    bool actA = (kt <= qtA);
    int kv0 = kt * 64;
    const unsigned short* KsC = Ks[cur];
    const unsigned short* VsC = Vs[cur];

    // S^T = mfma(K, Q): D[key][q], q = lo, key = kv0 + nt*16 + hi*4 + r
    f32x4 sB[4], sA[4];
    __builtin_amdgcn_s_setprio(1);
#pragma unroll
    for (int nt = 0; nt < 4; ++nt) {
      int rrow = (nt * 16 + lo) * 64;
      int c0 = (hi * 8) ^ swz;
      bf16x8 kf0 = *(const bf16x8*)&KsC[rrow + c0];
      bf16x8 kf1 = *(const bf16x8*)&KsC[rrow + (c0 ^ 32)];
      f32x4 a = (f32x4){0.f, 0.f, 0.f, 0.f};
      a = __builtin_amdgcn_mfma_f32_16x16x32_bf16(kf0, qB0, a, 0, 0, 0);
      a = __builtin_amdgcn_mfma_f32_16x16x32_bf16(kf1, qB1, a, 0, 0, 0);
      sB[nt] = a;
      if (actA) {
        f32x4 aa = (f32x4){0.f, 0.f, 0.f, 0.f};
        aa = __builtin_amdgcn_mfma_f32_16x16x32_bf16(kf0, qA0, aa, 0, 0, 0);
        aa = __builtin_amdgcn_mfma_f32_16x16x32_bf16(kf1, qA1, aa, 0, 0, 0);
        sA[nt] = aa;
      }
    }
    __builtin_amdgcn_s_setprio(0);

    if (kt == qtB) {
#pragma unroll
      for (int nt = 0; nt < 4; ++nt)
#pragma unroll
        for (int r = 0; r < 4; ++r)
          if (kv0 + nt * 16 + hi * 4 + r > q0B + lo) sB[nt][r] = -1e30f;
    }
    if (actA && kt == qtA) {
#pragma unroll
      for (int nt = 0; nt < 4; ++nt)
#pragma unroll
        for (int r = 0; r < 4; ++r)
          if (kv0 + nt * 16 + hi * 4 + r > q0A + lo) sA[nt][r] = -1e30f;
    }

    softmax_state(sB, mB, lB, yB, &Ps[0][w * 1024], lo, hi, swz);
    if (actA) softmax_state(sA, mA, lA, yA, &Ps[1][w * 1024], lo, hi, swz);

    // PV: y[q][d] += P[q][k] * V[k][d]; V frags shared across states
    __builtin_amdgcn_s_setprio(1);
#pragma unroll
    for (int kc = 0; kc < 2; ++kc) {
      int pcol = (kc * 32 + hi * 8) ^ swz;
      bf16x8 paB = *(const bf16x8*)&Ps[0][w * 1024 + lo * 64 + pcol];
      bf16x8 paA;
      if (actA) paA = *(const bf16x8*)&Ps[1][w * 1024 + lo * 64 + pcol];
#pragma unroll
      for (int nf = 0; nf < 4; ++nf) {
        bf16x8 vf = *(const bf16x8*)&VsC[(nf * 16 + lo) * 64 + pcol];
        yB[nf] = __builtin_amdgcn_mfma_f32_16x16x32_bf16(paB, vf, yB[nf], 0, 0, 0);
        if (actA) yA[nf] = __builtin_amdgcn_mfma_f32_16x16x32_bf16(paA, vf, yA[nf], 0, 0, 0);
      }
    }
    __builtin_amdgcn_s_setprio(0);

    __syncthreads();  // drains prefetch vmcnt + fences LDS reuse
    cur ^= 1;
  }

  // epilogue: reduce per-lane partial sums, divide, store
  lA += __shfl_xor(lA, 16); lA += __shfl_xor(lA, 32);
  lB += __shfl_xor(lB, 16); lB += __shfl_xor(lB, 32);
  float invA = 1.0f / lA, invB = 1.0f / lB;
#pragma unroll
  for (int r = 0; r < 4; ++r) {
    float iA = __shfl(invA, hi * 4 + r);
    float iB = __shfl(invB, hi * 4 + r);
    int tA = q0A + hi * 4 + r, tB = q0B + hi * 4 + r;
    __bf16* ypA = (__bf16*)(Y + ((size_t)(b * T_ + tA)) * D_ + h * 64);
    __bf16* ypB = (__bf16*)(Y + ((size_t)(b * T_ + tB)) * D_ + h * 64);
#pragma unroll
    for (int nf = 0; nf < 4; ++nf) {
      ypA[nf * 16 + lo] = (__bf16)(yA[nf][r] * iA);
      ypB[nf * 16 + lo] = (__bf16)(yB[nf][r] * iB);
    }
  }
}

extern "C" void kernel_launch(void* const* d_in, const int* in_sizes, int n_in,
                              void* d_out, int out_size, void* d_ws, size_t ws_size,
                              hipStream_t stream) {
  const float* x     = (const float*)d_in[0];
  const float* cosT  = (const float*)d_in[1];
  const float* sinT  = (const float*)d_in[2];
  const float* v0    = (const float*)d_in[3];
  const float* Wqkv  = (const float*)d_in[4];
  const float* Wproj = (const float*)d_in[5];
  const float* vrl   = (const float*)d_in[6];
  const float* qks   = (const float*)d_in[7];
  float* out = (float*)d_out;

  char* ws = (char*)d_ws;
  unsigned short* xb     = (unsigned short*)ws;                   //  8388608 B
  unsigned short* wqkvb  = (unsigned short*)(ws + 8388608);       //  3145728 B
  unsigned short* wprojb = (unsigned short*)(ws + 11534336);      //  2097152 B
  unsigned short* qb     = (unsigned short*)(ws + 13631488);      //  8388608 B
  unsigned short* kb     = (unsigned short*)(ws + 22020096);      //  2097152 B
  unsigned short* vb     = (unsigned short*)(ws + 24117248);      //  8388608 B (V^T swizzled)
  unsigned short* yb     = (unsigned short*)(ws + 32505856);      //  8388608 B

  k_convert_all<<<5376, 256, 0, stream>>>(x, Wqkv, Wproj, v0, xb, wqkvb, wprojb,
                                          out + 4194304);

  k_gemm_qkv<<<dim3(E_ / 128, (B_ * T_) / 128), 256, 0, stream>>>(
      xb, wqkvb, cosT, sinT, v0, vrl, qks, qb, kb, vb);

  k_attn<<<dim3(16, NH_, B_), 256, 0, stream>>>(qb, kb, vb, yb);

  k_gemm_bt<<<dim3(D_ / 128, (B_ * T_) / 128), 256, 0, stream>>>(yb, wprojb, out, B_ * T_, D_, D_);
}

// Round 5
// 117.064 us; speedup vs baseline: 2.2868x; 1.2181x over previous
//
#include <hip/hip_runtime.h>
#include <hip/hip_bf16.h>

#define B_   2
#define T_   2048
#define D_   1024
#define NH_  16
#define NKV_ 4
#define HD_  64
#define E_   1536  // (NH + 2*NKV) * HD
#define LOG2E 1.4426950408889634f

typedef __attribute__((ext_vector_type(8))) __bf16 bf16x8;
typedef __attribute__((ext_vector_type(4))) __bf16 bf16x4;
typedef __attribute__((ext_vector_type(4))) float f32x4;

// async global->LDS, 16B per lane. LDS dest = wave-uniform base + lane*16.
static __device__ __forceinline__ void gld_lds16(const unsigned short* g, unsigned short* l) {
  __builtin_amdgcn_global_load_lds(
      (const __attribute__((address_space(1))) unsigned int*)(unsigned long long)(const void*)g,
      (__attribute__((address_space(3))) unsigned int*)(unsigned int)(unsigned long long)(void*)l,
      16, 0, 0);
}

// raw hardware ops (avoid OCML guard sequences; args bounded, FTZ exact for us)
static __device__ __forceinline__ float fexp2(float x) {
  float r; asm("v_exp_f32 %0, %1" : "=v"(r) : "v"(x)); return r;
}
static __device__ __forceinline__ float fmax3(float a, float b, float c) {
  float r; asm("v_max3_f32 %0, %1, %2, %3" : "=v"(r) : "v"(a), "v"(b), "v"(c)); return r;
}
static __device__ __forceinline__ float frcp(float x) {
  float r; asm("v_rcp_f32 %0, %1" : "=v"(r) : "v"(x)); return r;
}

// ------------- weight fp32->bf16 converts + v0 passthrough copy -------------
__global__ void k_convert_all(const float* __restrict__ wq, const float* __restrict__ wp,
                              const float* __restrict__ v0,
                              unsigned short* __restrict__ wqb, unsigned short* __restrict__ wpb,
                              float* __restrict__ out2) {
  int i = blockIdx.x * blockDim.x + threadIdx.x;
  if (i < 327680) {
    const float* src; unsigned short* dst; int j;
    if (i < 196608) { src = wq; dst = wqb; j = i; }
    else            { src = wp; dst = wpb; j = i - 196608; }
    const float4* p = (const float4*)src + (size_t)j * 2;
    float4 a = p[0], b = p[1];
    bf16x8 o;
    o[0] = (__bf16)a.x; o[1] = (__bf16)a.y; o[2] = (__bf16)a.z; o[3] = (__bf16)a.w;
    o[4] = (__bf16)b.x; o[5] = (__bf16)b.y; o[6] = (__bf16)b.z; o[7] = (__bf16)b.w;
    ((bf16x8*)dst)[j] = o;
  } else {
    int j = i - 327680;  // 524288 units of 8 floats
    const float4* p = (const float4*)v0 + (size_t)j * 2;
    float4* q = (float4*)out2 + (size_t)j * 2;
    q[0] = p[0]; q[1] = p[1];
  }
}

// ---------------- QKV GEMM: f32 x (reg-staged+cvt) * bf16 W^T, fused epilogue ----------------
// tile 128Mx64N, BK=64, 2-phase prefetch. grid (24, 32) = 768 blocks (3/CU).
// Each block's 64-col tile = exactly one head (bn = head group id).
__global__ __launch_bounds__(256) void k_gemm_qkv(
    const float* __restrict__ X,
    const unsigned short* __restrict__ W,
    const float* __restrict__ cosT, const float* __restrict__ sinT,
    const float* __restrict__ v0,
    const float* __restrict__ vrl, const float* __restrict__ qks,
    unsigned short* __restrict__ qb, unsigned short* __restrict__ kb,
    unsigned short* __restrict__ vb) {
  __shared__ __align__(16) unsigned short As[2][128 * 64];
  __shared__ __align__(16) unsigned short Ws[2][64 * 64];
  int tid = threadIdx.x;
  int w = tid >> 6, l = tid & 63, lo = l & 15, hi = l >> 4;
  int f = blockIdx.y * 24 + blockIdx.x;           // 768 blocks, %8==0
  int f2 = (f & 7) * 96 + (f >> 3);               // XCD swizzle
  int bn = f2 % 24, bm = f2 / 24;

  const float* Xb = X + (size_t)bm * 128 * 1024;
  const unsigned short* Wb = W + (size_t)bn * 64 * 1024;

  f32x4 acc[2][4];
#pragma unroll
  for (int mi = 0; mi < 2; ++mi)
#pragma unroll
    for (int ni = 0; ni < 4; ++ni) acc[mi][ni] = (f32x4){0.f, 0.f, 0.f, 0.f};

  int ar = tid >> 2, ac = (tid & 3) * 16;  // A staging: rows ar, ar+64; 16 f32 each
  float4 fa[2][4];

#define LOADA(kt) {                                                            \
  int k0 = (kt) * 64;                                                         \
  _Pragma("unroll") for (int ii = 0; ii < 2; ++ii)                            \
  _Pragma("unroll") for (int j = 0; j < 4; ++j)                               \
    fa[ii][j] = *(const float4*)(Xb + (size_t)(ar + ii * 64) * 1024 + k0 + ac + j * 4); }

#define WRITEA(buf) {                                                          \
  _Pragma("unroll") for (int ii = 0; ii < 2; ++ii) {                          \
    bf16x8 o0, o1;                                                            \
    o0[0] = (__bf16)fa[ii][0].x; o0[1] = (__bf16)fa[ii][0].y;                 \
    o0[2] = (__bf16)fa[ii][0].z; o0[3] = (__bf16)fa[ii][0].w;                 \
    o0[4] = (__bf16)fa[ii][1].x; o0[5] = (__bf16)fa[ii][1].y;                 \
    o0[6] = (__bf16)fa[ii][1].z; o0[7] = (__bf16)fa[ii][1].w;                 \
    o1[0] = (__bf16)fa[ii][2].x; o1[1] = (__bf16)fa[ii][2].y;                 \
    o1[2] = (__bf16)fa[ii][2].z; o1[3] = (__bf16)fa[ii][2].w;                 \
    o1[4] = (__bf16)fa[ii][3].x; o1[5] = (__bf16)fa[ii][3].y;                 \
    o1[6] = (__bf16)fa[ii][3].z; o1[7] = (__bf16)fa[ii][3].w;                 \
    *(bf16x8*)&As[buf][(ar + ii * 64) * 64 + ac] = o0;                        \
    *(bf16x8*)&As[buf][(ar + ii * 64) * 64 + ac + 8] = o1; } }

#define STAGEW(kt, buf) {                                                      \
  int k0 = (kt) * 64;                                                         \
  _Pragma("unroll") for (int ii = 0; ii < 2; ++ii) {                          \
    int sb = ii * 256 + w * 64;                                               \
    gld_lds16(Wb + (size_t)((sb + l) >> 3) * 1024 + k0 + ((sb + l) & 7) * 8,  \
              &Ws[buf][sb * 8]); } }

  LOADA(0); STAGEW(0, 0); WRITEA(0);
  __syncthreads();

  for (int kt = 0; kt < 16; ++kt) {
    int cur = kt & 1;
    bool pf = (kt + 1) < 16;
    if (pf) { LOADA(kt + 1); STAGEW(kt + 1, cur ^ 1); }
    __builtin_amdgcn_s_setprio(1);
#pragma unroll
    for (int kk = 0; kk < 2; ++kk) {
      bf16x8 af0 = *(const bf16x8*)&As[cur][(w * 32 + lo) * 64 + kk * 32 + hi * 8];
      bf16x8 af1 = *(const bf16x8*)&As[cur][(w * 32 + 16 + lo) * 64 + kk * 32 + hi * 8];
#pragma unroll
      for (int ni = 0; ni < 4; ++ni) {
        bf16x8 wf = *(const bf16x8*)&Ws[cur][(ni * 16 + lo) * 64 + kk * 32 + hi * 8];
        acc[0][ni] = __builtin_amdgcn_mfma_f32_16x16x32_bf16(af0, wf, acc[0][ni], 0, 0, 0);
        acc[1][ni] = __builtin_amdgcn_mfma_f32_16x16x32_bf16(af1, wf, acc[1][ni], 0, 0, 0);
      }
    }
    __builtin_amdgcn_s_setprio(0);
    if (pf) WRITEA(cur ^ 1);
    __syncthreads();
  }
#undef LOADA
#undef WRITEA
#undef STAGEW

  // epilogue: bn = head group (0-15 q, 16-19 k, 20-23 v)
  if (bn < 20) {
    int isq = (bn < 16);
    int h = isq ? bn : bn - 16;
    float sc = isq ? (qks[h] * (LOG2E / 64.0f)) : 1.0f;
    unsigned short* base = isq ? qb : kb;
    int nheads = isq ? NH_ : NKV_;
#pragma unroll
    for (int mi = 0; mi < 2; ++mi) {
#pragma unroll
      for (int r = 0; r < 4; ++r) {
        int row = bm * 128 + w * 32 + mi * 16 + hi * 4 + r;
        int b = row >> 11, t = row & 2047;
        float c = cosT[t * 16 + lo], s = sinT[t * 16 + lo];
        float a0 = acc[mi][0][r], a1 = acc[mi][1][r];
        __bf16* dp = (__bf16*)(base + ((size_t)(b * nheads + h) * T_ + t) * 64);
        int ts = isq ? 0 : (8 * (t & 7));  // K stored d-swizzled for attn LDS reads
        dp[lo ^ ts]        = (__bf16)((a0 * c - a1 * s) * sc);
        dp[(16 + lo) ^ ts] = (__bf16)((a0 * s + a1 * c) * sc);
        dp[(32 + lo) ^ ts] = (__bf16)(acc[mi][2][r] * sc);
        dp[(48 + lo) ^ ts] = (__bf16)(acc[mi][3][r] * sc);
      }
    }
  } else {
    int hv = bn - 20;
    float av[4];
#pragma unroll
    for (int j = 0; j < 4; ++j) av[j] = 1.0f / (1.0f + __expf(-vrl[hv * 4 + j]));
#pragma unroll
    for (int mi = 0; mi < 2; ++mi) {
      int t0g = bm * 128 + w * 32 + mi * 16 + hi * 4;
      int b = t0g >> 11, t0 = t0g & 2047;
#pragma unroll
      for (int ni = 0; ni < 4; ++ni) {
        int d = ni * 16 + lo;
#pragma unroll
        for (int j = 0; j < 4; ++j) {
          float a = av[j], na = 1.0f - a;
          const float* v0p = v0 + ((size_t)(b * NH_ + hv * 4 + j) * T_ + t0) * 64 + d;
          bf16x4 vv;
#pragma unroll
          for (int r = 0; r < 4; ++r)
            vv[r] = (__bf16)(na * acc[mi][ni][r] + a * v0p[(size_t)r * 64]);
          // v^T store: [b][h][d][t], t swizzled within 64-block by 8*(d&7)
          *(bf16x4*)((unsigned short*)vb + ((size_t)(b * NH_ + hv * 4 + j) * 64 + d) * T_ +
                     (t0 ^ (8 * (lo & 7)))) = vv;
        }
      }
    }
  }
}

// ---------------- proj GEMM: C[M,N] = A[M,K]*W[N,K]^T, bf16 in fp32 out ----------
// tile 128Mx64N, BK=64, 2-phase, gld_lds both operands. grid (16,32) = 512 blocks.
__global__ __launch_bounds__(256) void k_gemm_bt(
    const unsigned short* __restrict__ A,
    const unsigned short* __restrict__ W,
    float* __restrict__ C, int K) {
  __shared__ __align__(16) unsigned short As[2][128 * 64];
  __shared__ __align__(16) unsigned short Ws[2][64 * 64];
  int tid = threadIdx.x;
  int w = tid >> 6, l = tid & 63, lo = l & 15, hi = l >> 4;
  int f = blockIdx.y * 16 + blockIdx.x;  // 512 blocks
  int f2 = (f & 7) * 64 + (f >> 3);
  int bn = f2 % 16, bm = f2 / 16;

  const unsigned short* Ab = A + (size_t)bm * 128 * K;
  const unsigned short* Wb = W + (size_t)bn * 64 * K;

  f32x4 acc[2][4];
#pragma unroll
  for (int mi = 0; mi < 2; ++mi)
#pragma unroll
    for (int ni = 0; ni < 4; ++ni) acc[mi][ni] = (f32x4){0.f, 0.f, 0.f, 0.f};

#define STAGE(kt, buf) {                                                       \
  int k0 = (kt) * 64;                                                         \
  _Pragma("unroll") for (int ii = 0; ii < 4; ++ii) {                          \
    int sb = ii * 256 + w * 64;                                               \
    gld_lds16(Ab + (size_t)((sb + l) >> 3) * K + k0 + ((sb + l) & 7) * 8,     \
              &As[buf][sb * 8]); }                                            \
  _Pragma("unroll") for (int ii = 0; ii < 2; ++ii) {                          \
    int sb = ii * 256 + w * 64;                                               \
    gld_lds16(Wb + (size_t)((sb + l) >> 3) * K + k0 + ((sb + l) & 7) * 8,     \
              &Ws[buf][sb * 8]); } }

  STAGE(0, 0);
  __syncthreads();
  int nkt = K / 64;
  for (int kt = 0; kt < nkt; ++kt) {
    int cur = kt & 1;
    bool pf = (kt + 1) < nkt;
    if (pf) STAGE(kt + 1, cur ^ 1);
    __builtin_amdgcn_s_setprio(1);
#pragma unroll
    for (int kk = 0; kk < 2; ++kk) {
      bf16x8 af0 = *(const bf16x8*)&As[cur][(w * 32 + lo) * 64 + kk * 32 + hi * 8];
      bf16x8 af1 = *(const bf16x8*)&As[cur][(w * 32 + 16 + lo) * 64 + kk * 32 + hi * 8];
#pragma unroll
      for (int ni = 0; ni < 4; ++ni) {
        bf16x8 wf = *(const bf16x8*)&Ws[cur][(ni * 16 + lo) * 64 + kk * 32 + hi * 8];
        acc[0][ni] = __builtin_amdgcn_mfma_f32_16x16x32_bf16(af0, wf, acc[0][ni], 0, 0, 0);
        acc[1][ni] = __builtin_amdgcn_mfma_f32_16x16x32_bf16(af1, wf, acc[1][ni], 0, 0, 0);
      }
    }
    __builtin_amdgcn_s_setprio(0);
    __syncthreads();
  }
#undef STAGE

#pragma unroll
  for (int mi = 0; mi < 2; ++mi) {
#pragma unroll
    for (int r = 0; r < 4; ++r) {
      int row = bm * 128 + w * 32 + mi * 16 + hi * 4 + r;
      float* cp = C + (size_t)row * D_ + bn * 64 + lo;
#pragma unroll
      for (int ni = 0; ni < 4; ++ni) cp[ni * 16] = acc[mi][ni][r];
    }
  }
}

// ---------------- flash attention: gld_lds staging, swizzled LDS, paired q-tiles ---------
static __device__ __forceinline__ void stage_kv(const unsigned short* Kb, const unsigned short* Vb,
                                                int kv0, int w, int l,
                                                unsigned short* KsB, unsigned short* VsB) {
#pragma unroll
  for (int i = 0; i < 2; ++i) {
    int ch = w + 4 * i;  // 1KB chunk id, 8 chunks per 8KB tile
    gld_lds16(Kb + (size_t)kv0 * 64 + ch * 512 + l * 8, KsB + ch * 512);
    gld_lds16(Vb + (size_t)(ch * 8 + (l >> 3)) * T_ + kv0 + (l & 7) * 8, VsB + ch * 512);
  }
}

// online softmax in exp2 domain, defer-max (THR=8), per-lane partial lsum
__device__ __forceinline__ void softmax_state(f32x4 (&s)[4], float& m, float& lsum,
                                              f32x4 (&y)[4], unsigned short* PsW,
                                              int lo, int hi, int swz) {
  float a0 = fmax3(s[0][0], s[0][1], s[0][2]);
  float a1 = fmax3(s[0][3], s[1][0], s[1][1]);
  float a2 = fmax3(s[1][2], s[1][3], s[2][0]);
  float a3 = fmax3(s[2][1], s[2][2], s[2][3]);
  float a4 = fmax3(s[3][0], s[3][1], s[3][2]);
  float pm = fmaxf(fmax3(a0, a1, a2), fmax3(a3, a4, s[3][3]));
  if (!__all(pm <= m + 8.0f)) {  // rare after first tile
    pm = fmaxf(pm, __shfl_xor(pm, 16));
    pm = fmaxf(pm, __shfl_xor(pm, 32));
    float mnew = fmaxf(m, pm);
    float sc = fexp2(m - mnew);
    lsum *= sc;
#pragma unroll
    for (int r = 0; r < 4; ++r) {
      float scr = __shfl(sc, hi * 4 + r);
#pragma unroll
      for (int nf = 0; nf < 4; ++nf) y[nf][r] *= scr;
    }
    m = mnew;
  }
  float rs = 0.f;
#pragma unroll
  for (int nt = 0; nt < 4; ++nt) {
    float p0 = fexp2(s[nt][0] - m);
    float p1 = fexp2(s[nt][1] - m);
    float p2 = fexp2(s[nt][2] - m);
    float p3 = fexp2(s[nt][3] - m);
    rs += (p0 + p1) + (p2 + p3);
    bf16x4 pk;
    pk[0] = (__bf16)p0; pk[1] = (__bf16)p1; pk[2] = (__bf16)p2; pk[3] = (__bf16)p3;
    *(bf16x4*)(PsW + lo * 64 + ((nt * 16 + hi * 4) ^ swz)) = pk;
  }
  lsum += rs;
}

__global__ __launch_bounds__(256) void k_attn(const unsigned short* __restrict__ Q,
                                              const unsigned short* __restrict__ Kp,
                                              const unsigned short* __restrict__ Vtp,
                                              unsigned short* __restrict__ Y) {
  int p = blockIdx.x, h = blockIdx.y, b = blockIdx.z;
  int tid = threadIdx.x;
  int w = tid >> 6, l = tid & 63, lo = l & 15, hi = l >> 4;
  int kh = h >> 2;
  int qtA = p, qtB = 31 - p;
  int ntB = qtB + 1;
  int q0A = qtA * 64 + w * 16, q0B = qtB * 64 + w * 16;
  int swz = 8 * (lo & 7);

  __shared__ __align__(16) unsigned short Ks[2][4096];
  __shared__ __align__(16) unsigned short Vs[2][4096];
  __shared__ __align__(16) unsigned short Ps[2][4096];  // [state][w*1024 + row*64 + col]

  const unsigned short* Qb = Q + ((size_t)(b * NH_ + h) * T_) * 64;
  const unsigned short* Kb = Kp + ((size_t)(b * NKV_ + kh) * T_) * 64;
  const unsigned short* Vb = Vtp + ((size_t)(b * NH_ + h) * 64) * T_;

  bf16x8 qA0 = *(const bf16x8*)(Qb + (size_t)(q0A + lo) * 64 + hi * 8);
  bf16x8 qA1 = *(const bf16x8*)(Qb + (size_t)(q0A + lo) * 64 + 32 + hi * 8);
  bf16x8 qB0 = *(const bf16x8*)(Qb + (size_t)(q0B + lo) * 64 + hi * 8);
  bf16x8 qB1 = *(const bf16x8*)(Qb + (size_t)(q0B + lo) * 64 + 32 + hi * 8);

  f32x4 yA[4], yB[4];
#pragma unroll
  for (int nf = 0; nf < 4; ++nf) {
    yA[nf] = (f32x4){0.f, 0.f, 0.f, 0.f};
    yB[nf] = (f32x4){0.f, 0.f, 0.f, 0.f};
  }
  float mA = -INFINITY, lA = 0.f, mB = -INFINITY, lB = 0.f;

  stage_kv(Kb, Vb, 0, w, l, Ks[0], Vs[0]);
  __syncthreads();
  int cur = 0;

  for (int kt = 0; kt < ntB; ++kt) {
    bool pf = (kt + 1) < ntB;
    if (pf) stage_kv(Kb, Vb, (kt + 1) * 64, w, l, Ks[cur ^ 1], Vs[cur ^ 1]);
    bool actA = (kt <= qtA);
    int kv0 = kt * 64;
    const unsigned short* KsC = Ks[cur];
    const unsigned short* VsC = Vs[cur];

    // S^T = mfma(K, Q): D[key][q], q = lo, key = kv0 + nt*16 + hi*4 + r
    f32x4 sB[4], sA[4];
    __builtin_amdgcn_s_setprio(1);
#pragma unroll
    for (int nt = 0; nt < 4; ++nt) {
      int rrow = (nt * 16 + lo) * 64;
      int c0 = (hi * 8) ^ swz;
      bf16x8 kf0 = *(const bf16x8*)&KsC[rrow + c0];
      bf16x8 kf1 = *(const bf16x8*)&KsC[rrow + (c0 ^ 32)];
      f32x4 a = (f32x4){0.f, 0.f, 0.f, 0.f};
      a = __builtin_amdgcn_mfma_f32_16x16x32_bf16(kf0, qB0, a, 0, 0, 0);
      a = __builtin_amdgcn_mfma_f32_16x16x32_bf16(kf1, qB1, a, 0, 0, 0);
      sB[nt] = a;
      if (actA) {
        f32x4 aa = (f32x4){0.f, 0.f, 0.f, 0.f};
        aa = __builtin_amdgcn_mfma_f32_16x16x32_bf16(kf0, qA0, aa, 0, 0, 0);
        aa = __builtin_amdgcn_mfma_f32_16x16x32_bf16(kf1, qA1, aa, 0, 0, 0);
        sA[nt] = aa;
      }
    }
    __builtin_amdgcn_s_setprio(0);

    if (kt == qtB) {
#pragma unroll
      for (int nt = 0; nt < 4; ++nt)
#pragma unroll
        for (int r = 0; r < 4; ++r)
          if (kv0 + nt * 16 + hi * 4 + r > q0B + lo) sB[nt][r] = -1e30f;
    }
    if (actA && kt == qtA) {
#pragma unroll
      for (int nt = 0; nt < 4; ++nt)
#pragma unroll
        for (int r = 0; r < 4; ++r)
          if (kv0 + nt * 16 + hi * 4 + r > q0A + lo) sA[nt][r] = -1e30f;
    }

    softmax_state(sB, mB, lB, yB, &Ps[0][w * 1024], lo, hi, swz);
    if (actA) softmax_state(sA, mA, lA, yA, &Ps[1][w * 1024], lo, hi, swz);

    // PV: y[q][d] += P[q][k] * V[k][d]; V frags shared across states
    __builtin_amdgcn_s_setprio(1);
#pragma unroll
    for (int kc = 0; kc < 2; ++kc) {
      int pcol = (kc * 32 + hi * 8) ^ swz;
      bf16x8 paB = *(const bf16x8*)&Ps[0][w * 1024 + lo * 64 + pcol];
      bf16x8 paA;
      if (actA) paA = *(const bf16x8*)&Ps[1][w * 1024 + lo * 64 + pcol];
#pragma unroll
      for (int nf = 0; nf < 4; ++nf) {
        bf16x8 vf = *(const bf16x8*)&VsC[(nf * 16 + lo) * 64 + pcol];
        yB[nf] = __builtin_amdgcn_mfma_f32_16x16x32_bf16(paB, vf, yB[nf], 0, 0, 0);
        if (actA) yA[nf] = __builtin_amdgcn_mfma_f32_16x16x32_bf16(paA, vf, yA[nf], 0, 0, 0);
      }
    }
    __builtin_amdgcn_s_setprio(0);

    __syncthreads();  // drains prefetch vmcnt + fences LDS reuse
    cur ^= 1;
  }

  // epilogue: reduce per-lane partial sums, divide, store
  lA += __shfl_xor(lA, 16); lA += __shfl_xor(lA, 32);
  lB += __shfl_xor(lB, 16); lB += __shfl_xor(lB, 32);
  float invA = frcp(lA), invB = frcp(lB);
#pragma unroll
  for (int r = 0; r < 4; ++r) {
    float iA = __shfl(invA, hi * 4 + r);
    float iB = __shfl(invB, hi * 4 + r);
    int tA = q0A + hi * 4 + r, tB = q0B + hi * 4 + r;
    __bf16* ypA = (__bf16*)(Y + ((size_t)(b * T_ + tA)) * D_ + h * 64);
    __bf16* ypB = (__bf16*)(Y + ((size_t)(b * T_ + tB)) * D_ + h * 64);
#pragma unroll
    for (int nf = 0; nf < 4; ++nf) {
      ypA[nf * 16 + lo] = (__bf16)(yA[nf][r] * iA);
      ypB[nf * 16 + lo] = (__bf16)(yB[nf][r] * iB);
    }
  }
}

extern "C" void kernel_launch(void* const* d_in, const int* in_sizes, int n_in,
                              void* d_out, int out_size, void* d_ws, size_t ws_size,
                              hipStream_t stream) {
  const float* x     = (const float*)d_in[0];
  const float* cosT  = (const float*)d_in[1];
  const float* sinT  = (const float*)d_in[2];
  const float* v0    = (const float*)d_in[3];
  const float* Wqkv  = (const float*)d_in[4];
  const float* Wproj = (const float*)d_in[5];
  const float* vrl   = (const float*)d_in[6];
  const float* qks   = (const float*)d_in[7];
  float* out = (float*)d_out;

  char* ws = (char*)d_ws;
  unsigned short* wqkvb  = (unsigned short*)ws;                   //  3145728 B
  unsigned short* wprojb = (unsigned short*)(ws + 3145728);       //  2097152 B
  unsigned short* qb     = (unsigned short*)(ws + 5242880);       //  8388608 B
  unsigned short* kb     = (unsigned short*)(ws + 13631488);      //  2097152 B
  unsigned short* vb     = (unsigned short*)(ws + 15728640);      //  8388608 B (V^T swizzled)
  unsigned short* yb     = (unsigned short*)(ws + 24117248);      //  8388608 B

  k_convert_all<<<3328, 256, 0, stream>>>(Wqkv, Wproj, v0, wqkvb, wprojb, out + 4194304);

  k_gemm_qkv<<<dim3(24, 32), 256, 0, stream>>>(x, wqkvb, cosT, sinT, v0, vrl, qks, qb, kb, vb);

  k_attn<<<dim3(16, NH_, B_), 256, 0, stream>>>(qb, kb, vb, yb);

  k_gemm_bt<<<dim3(16, 32), 256, 0, stream>>>(yb, wprojb, out, D_);
}